// Round 1
// baseline (379.974 us; speedup 1.0000x reference)
//
#include <hip/hip_runtime.h>
#include <hip/hip_bf16.h>

#define EMB 256

typedef __bf16 bf16_t;
typedef __attribute__((ext_vector_type(8))) __bf16 bf16x8;
typedef __attribute__((ext_vector_type(4))) __bf16 bf16x4;
typedef __attribute__((ext_vector_type(4))) float floatx4;

// ---------- helpers ----------
__device__ __forceinline__ int eidx(const int* __restrict__ p, int is64, long long k){
  return is64 ? p[2*k] : p[(int)k];
}
__device__ __forceinline__ float4 cvt4(bf16x4 v){
  return make_float4((float)v.x, (float)v.y, (float)v.z, (float)v.w);
}

// ---------- dtype detect ----------
__global__ void detect_kernel(const int* __restrict__ ei, int* __restrict__ flag){
  int z = (ei[1]==0) + (ei[3]==0) + (ei[5]==0) + (ei[7]==0);
  *flag = (z == 4) ? 1 : 0;
}

// ---------- x -> bf16 ----------
__global__ void cvt_x_kernel(const float* __restrict__ x, bf16_t* __restrict__ xb, int n4){
  int t = blockIdx.x*blockDim.x + threadIdx.x;
  if (t >= n4) return;
  const float4 v = *(const float4*)(x + (size_t)t*4);
  bf16x4 o = { (bf16_t)v.x, (bf16_t)v.y, (bf16_t)v.z, (bf16_t)v.w };
  *(bf16x4*)(xb + (size_t)t*4) = o;
}

// ---------- fold W1 into Wkqv; emit TRANSPOSED bf16 WcombT[768][256] + fp32 bcomb[768] ----------
// Output column layout (KV-PACKED): cols [0,256) = q (h*128+d);
// cols [256,768): r = n-256, h = r>>8, g = (r&255)>>3, half = (r>>2)&1, dd = r&3, d = g*4+dd;
//   half 0 -> k_scaled[h][d], half 1 -> v[h][d].
__global__ void prep_weights(const float* __restrict__ Wkqv, const float* __restrict__ bkqv,
                             const float* __restrict__ W1,
                             bf16_t* __restrict__ WcombT, float* __restrict__ bcomb){
  int n = blockIdx.x * blockDim.x + threadIdx.x;   // 0..767 (output col, permuted layout)
  int c = blockIdx.y;                              // 0..256 (k index; 256 = bias)
  if (n >= 768) return;
  const float rs = rsqrtf(128.0f);
  bool isBias = (c == 256);
  const float* arow = isBias ? bkqv : (Wkqv + (size_t)c*768);
  float val;
  if (n < 256){                       // q
    int h = n >> 7, d = n & 127;
    float s = 0.f;
    for (int t = 0; t < 128; ++t)
      s = fmaf(arow[h*128 + t], W1[(size_t)(128 + t)*128 + d], s);
    val = s;
  } else {
    int r = n - 256;
    int h = r >> 8, t8 = r & 255;
    int g = t8 >> 3, half = (t8 >> 2) & 1, dd = t8 & 3;
    int d = g*4 + dd;
    if (half == 0){                   // k (scaled)
      float s = 0.f;
      for (int t = 0; t < 128; ++t)
        s = fmaf(arow[256 + h*128 + t], W1[(size_t)t*128 + d], s);
      val = s * rs;
    } else {                          // v passthrough
      val = arow[512 + h*128 + d];
    }
  }
  if (isBias) bcomb[n] = val;
  else        WcombT[(size_t)n*256 + c] = (bf16_t)val;
}

// ---------- Wout -> transposed bf16 WoutT[256][256] ----------
__global__ void prep_wout(const float* __restrict__ W, bf16_t* __restrict__ Wt){
  int t = blockIdx.x*blockDim.x + threadIdx.x;  // 65536
  int n = t & 255, c = t >> 8;
  Wt[(size_t)n*256 + c] = (bf16_t)W[(size_t)c*256 + n];
}

// ---------- degree count over the 2*E0 non-self edges (dst side) ----------
__global__ void deg_kernel(const int* __restrict__ ei, const int* __restrict__ flag,
                           int* __restrict__ deg, int E0, int Nn){
  int t = blockIdx.x*blockDim.x + threadIdx.x;
  if (t >= 2*E0) return;
  int is64 = *flag;
  int i = (t < E0) ? eidx(ei,is64,(long long)E0+t) : eidx(ei,is64,t-E0);
  i = min(max(i,0), Nn-1);
  atomicAdd(deg + i, 1);
}

// ---------- exclusive prefix scan of (deg+1) -> off[0..N] (self-loop slot included) ----------
__global__ __launch_bounds__(1024) void scan_kernel(const int* __restrict__ deg,
                                                    int* __restrict__ off, int N){
  __shared__ int wsum[16];
  __shared__ int carry_s;
  int tid = threadIdx.x, lane = tid & 63, w = tid >> 6;
  if (tid == 0) carry_s = 0;
  __syncthreads();
  for (int base = 0; base < N; base += 1024){
    int carry = carry_s;
    int v = (base + tid < N) ? (deg[base + tid] + 1) : 0;
    int incl = v;
    #pragma unroll
    for (int o = 1; o < 64; o <<= 1){
      int t = __shfl_up(incl, o, 64);
      if (lane >= o) incl += t;
    }
    if (lane == 63) wsum[w] = incl;
    __syncthreads();
    if (w == 0 && lane < 16){
      int sv = wsum[lane];
      #pragma unroll
      for (int o = 1; o < 16; o <<= 1){
        int t = __shfl_up(sv, o, 64);
        if (lane >= o) sv += t;
      }
      wsum[lane] = sv;
    }
    __syncthreads();
    int wpref = (w == 0) ? 0 : wsum[w-1];
    if (base + tid < N) off[base + tid] = carry + wpref + incl - v;
    __syncthreads();
    if (tid == 1023) carry_s = carry + wsum[15];
    __syncthreads();
  }
  if (threadIdx.x == 0) off[N] = carry_s;
}

// ---------- scatter source index j into CSR buckets (incl. self-loops) ----------
__global__ void scatter_kernel(const int* __restrict__ ei, const int* __restrict__ flag,
                               const int* __restrict__ off, int* __restrict__ cursor,
                               int* __restrict__ bj, int E0, int Nn){
  int e = blockIdx.x*blockDim.x + threadIdx.x;
  int E = 2*E0 + Nn;
  if (e >= E) return;
  int is64 = *flag;
  int j, i;
  if (e < E0){ j = eidx(ei,is64,e); i = eidx(ei,is64,(long long)E0+e); }
  else if (e < 2*E0){ int t = e - E0; i = eidx(ei,is64,t); j = eidx(ei,is64,(long long)E0+t); }
  else { i = j = e - 2*E0; }
  i = min(max(i,0), Nn-1); j = min(max(j,0), Nn-1);
  int pos = atomicAdd(cursor + i, 1);
  bj[off[i] + pos] = j;
}

// ---------- bf16 MFMA GEMM, K=256: C = A[M,256] @ Bt[N,256]^T + epilogue ----------
// BARRIER-FREE: fragments loaded directly from global (16B/lane, 64B-segment
// coalesced; identical lane->element mapping the LDS staging produced). K fully
// unrolled (8 steps) -> compiler software-pipelines up to 64 independent loads
// against 128 MFMAs. No LDS, no __syncthreads -> no vmcnt(0) barrier drain.
// Intra-block reuse is only across wave pairs (wm / wn sharing) -> L1 serves it;
// B is L2-resident (384 KB), A strip stays on one XCD via the swizzle.
// MODE 0: C(bf16) = AB + bias[n]
// MODE 1: C(fp32) = relu(AB + (deg[m]+1)*bias[n]) + xres[m*N+n]
template<int MODE, typename OutT>
__global__ __launch_bounds__(256, 4) void mfma_gemm(
    const bf16_t* __restrict__ A, const bf16_t* __restrict__ Bt,
    const float* __restrict__ bias, OutT* __restrict__ C,
    int M, int N,
    const int* __restrict__ deg, const float* __restrict__ xres)
{
  const int tid = threadIdx.x;
  const int wave = tid >> 6, lane = tid & 63;
  const int row16 = lane & 15, quad = lane >> 4;

  // XCD swizzle: bid%8 = XCD (dispatch round-robin heuristic); n fastest per XCD
  const int nn = N >> 7;
  const int bid = blockIdx.x;
  const int strip = bid / (8*nn);
  const int inner = bid % (8*nn);
  const int m0 = (strip*8 + (inner & 7)) * 128;
  const int n0 = (inner >> 3) * 128;
  const int wm = (wave >> 1) * 64, wn = (wave & 1) * 64;

  // per-fragment base pointers (A rows clamped for the padded tail strip)
  const bf16_t* Ap[4];
  const bf16_t* Bp[4];
  #pragma unroll
  for (int t = 0; t < 4; ++t){
    int rm = min(m0 + wm + t*16 + row16, M-1);
    Ap[t] = A  + (size_t)rm*256 + quad*8;
    Bp[t] = Bt + (size_t)(n0 + wn + t*16 + row16)*256 + quad*8;
  }

  floatx4 acc[4][4];
  #pragma unroll
  for (int a=0;a<4;++a)
    #pragma unroll
    for (int b=0;b<4;++b) acc[a][b] = (floatx4){0.f,0.f,0.f,0.f};

  #pragma unroll
  for (int kt = 0; kt < 8; ++kt){
    bf16x8 af[4], bfr[4];
    #pragma unroll
    for (int t = 0; t < 4; ++t){
      af[t]  = *(const bf16x8*)(Ap[t] + kt*32);
      bfr[t] = *(const bf16x8*)(Bp[t] + kt*32);
    }
    #pragma unroll
    for (int mt=0;mt<4;++mt)
      #pragma unroll
      for (int nt=0;nt<4;++nt)
        acc[mt][nt] = __builtin_amdgcn_mfma_f32_16x16x32_bf16(af[mt], bfr[nt], acc[mt][nt], 0,0,0);
  }

  // epilogue: C/D layout col=lane&15, row=quad*4+reg
  #pragma unroll
  for (int mt=0;mt<4;++mt){
    #pragma unroll
    for (int r=0;r<4;++r){
      int m = m0 + wm + mt*16 + quad*4 + r;
      if (m >= M) continue;
      float dg = (MODE==1) ? (float)(deg[m]+1) : 0.f;
      #pragma unroll
      for (int nt=0;nt<4;++nt){
        int n = n0 + wn + nt*16 + row16;
        float v = acc[mt][nt][r];
        if (MODE == 0){
          v += bias[n];
        } else {
          v = fmaxf(v + dg*bias[n], 0.f) + xres[(size_t)m*N + n];
        }
        C[(size_t)m*N + n] = (OutT)v;
      }
    }
  }
}

// ---------- fused attention: score + online softmax + aggregate, one wave per node ----------
// P layout: [0,256) q; [256,768) kv-packed: head h at 256+h*256, group g holds
// k[g*4..g*4+3] then v[g*4..g*4+3] -> ONE bf16x8 load per edge per lane.
__global__ __launch_bounds__(256) void fused_attn_kernel(
    const bf16_t* __restrict__ P, const int* __restrict__ bj, const int* __restrict__ off,
    const float* __restrict__ b1, const float* __restrict__ W2, const float* __restrict__ b2,
    bf16_t* __restrict__ aggb, int Nn)
{
  int i = blockIdx.x * (blockDim.x >> 6) + (threadIdx.x >> 6);
  if (i >= Nn) return;
  int lane = threadIdx.x & 63;
  int h = lane >> 5, g = lane & 31, d = g * 4;

  const float4 qv  = cvt4(*(const bf16x4*)(P + (size_t)i*768 + h*128 + d));
  const float4 b1v = *(const float4*)(b1 + d);
  const float4 w2v = *(const float4*)(W2 + d);
  const float b2v  = b2[0];

  float m = -3.0e38f, s = 0.f;
  float4 acc = make_float4(0.f,0.f,0.f,0.f);
  int s0 = off[i], s1 = off[i+1];
  for (int t = s0; t < s1; ++t){
    int j = bj[t];
    bf16x8 kvv = *(const bf16x8*)(P + (size_t)j*768 + 256 + h*256 + g*8);
    float kx = (float)kvv[0], ky = (float)kvv[1], kz = (float)kvv[2], kw = (float)kvv[3];
    float vx = (float)kvv[4], vy = (float)kvv[5], vz = (float)kvv[6], vw = (float)kvv[7];
    float p = fmaxf(qv.x+kx+b1v.x, 0.f)*w2v.x
            + fmaxf(qv.y+ky+b1v.y, 0.f)*w2v.y
            + fmaxf(qv.z+kz+b1v.z, 0.f)*w2v.z
            + fmaxf(qv.w+kw+b1v.w, 0.f)*w2v.w;
    // reduce across the 32-lane half-wave (bit5 = head, untouched)
    #pragma unroll
    for (int o = 16; o >= 1; o >>= 1)
      p += __shfl_xor(p, o, 64);
    float a = p + b2v;
    float mn = fmaxf(m, a);
    float sc = __expf(m - mn);
    float e  = __expf(a - mn);
    s = s*sc + e;
    acc.x = fmaf(acc.x, sc, e*vx);
    acc.y = fmaf(acc.y, sc, e*vy);
    acc.z = fmaf(acc.z, sc, e*vz);
    acc.w = fmaf(acc.w, sc, e*vw);
    m = mn;
  }
  float inv = 1.f / (s + 1e-16f);
  bf16x4 ob = { (bf16_t)(acc.x*inv), (bf16_t)(acc.y*inv), (bf16_t)(acc.z*inv), (bf16_t)(acc.w*inv) };
  *(bf16x4*)(aggb + (size_t)i*256 + h*128 + d) = ob;
}

// ---------- launch ----------
extern "C" void kernel_launch(void* const* d_in, const int* in_sizes, int n_in,
                              void* d_out, int out_size, void* d_ws, size_t ws_size,
                              hipStream_t stream)
{
  const float* x     = (const float*)d_in[0];
  const int*   ei    = (const int*)d_in[1];
  const float* Wkqv  = (const float*)d_in[2];
  const float* bkqv  = (const float*)d_in[3];
  const float* W1    = (const float*)d_in[4];
  const float* b1    = (const float*)d_in[5];
  const float* W2    = (const float*)d_in[6];
  const float* b2    = (const float*)d_in[7];
  const float* Wout  = (const float*)d_in[8];
  const float* bout  = (const float*)d_in[9];
  float* out = (float*)d_out;

  const int N  = in_sizes[0] / EMB;   // 50000
  const int E0 = in_sizes[1] / 2;     // 100000
  const int E  = 2*E0 + N;            // 250000

  // workspace layout (fp32-word offsets; all 16B-aligned)
  float* base = (float*)d_ws;
  bf16_t* WcombT = (bf16_t*)base;                       // 768*256 bf16
  float*  bcomb  = base + 98304;                        // 768 w
  bf16_t* WoutT  = (bf16_t*)(base + 98304 + 768);       // 256*256 bf16
  bf16_t* xb     = (bf16_t*)(base + 131840);            // N*256 bf16
  bf16_t* Pb     = (bf16_t*)(base + 131840 + 6400000);  // N*768 bf16
  bf16_t* aggb   = (bf16_t*)(Pb + (size_t)N*768);       // N*256 bf16
  int* deg       = (int*)(aggb + (size_t)N*256);        // N
  int* cursor    = deg + N;                             // N
  int* flag      = cursor + N;                          // 1
  int* off       = flag + 1;                            // N+1
  int* bj        = off + (N+1);                         // E

  hipMemsetAsync(deg, 0, (size_t)2*N*sizeof(int), stream);  // deg + cursor

  detect_kernel<<<1,1,0,stream>>>(ei, flag);
  cvt_x_kernel<<<((N*EMB/4)+255)/256,256,0,stream>>>(x, xb, N*EMB/4);
  prep_weights<<<dim3(3,257),256,0,stream>>>(Wkqv, bkqv, W1, WcombT, bcomb);
  prep_wout<<<256,256,0,stream>>>(Wout, WoutT);

  deg_kernel<<<(2*E0+255)/256,256,0,stream>>>(ei, flag, deg, E0, N);
  scan_kernel<<<1,1024,0,stream>>>(deg, off, N);
  scatter_kernel<<<(E+255)/256,256,0,stream>>>(ei, flag, off, cursor, bj, E0, N);

  const int nm8 = (((N+127)/128) + 7) & ~7;   // m-strips padded to multiple of 8
  mfma_gemm<0, bf16_t><<<nm8*6,256,0,stream>>>(xb, WcombT, bcomb, Pb, N, 768, nullptr, nullptr);
  fused_attn_kernel<<<(N+3)/4,256,0,stream>>>(Pb, bj, off, b1, W2, b2, aggb, N);
  mfma_gemm<1, float><<<nm8*2,256,0,stream>>>(aggb, WoutT, bout, out, N, 256, deg, x);
}

// Round 2
// 343.706 us; speedup vs baseline: 1.1055x; 1.1055x over previous
//
#include <hip/hip_runtime.h>
#include <hip/hip_bf16.h>

#define EMB 256

typedef __bf16 bf16_t;
typedef __attribute__((ext_vector_type(8))) __bf16 bf16x8;
typedef __attribute__((ext_vector_type(4))) __bf16 bf16x4;
typedef __attribute__((ext_vector_type(4))) float floatx4;

// ---------- helpers ----------
__device__ __forceinline__ int eidx(const int* __restrict__ p, int is64, long long k){
  return is64 ? p[2*k] : p[(int)k];
}
// async global->LDS, 16B per lane; LDS base must be WAVE-UNIFORM, lands at base + lane*16
__device__ __forceinline__ void async_load16(const void* g, void* l){
  __builtin_amdgcn_global_load_lds(
      (const __attribute__((address_space(1))) unsigned int*)g,
      (__attribute__((address_space(3))) unsigned int*)l,
      16, 0, 0);
}
__device__ __forceinline__ float4 cvt4(bf16x4 v){
  return make_float4((float)v.x, (float)v.y, (float)v.z, (float)v.w);
}

// ---------- dtype detect ----------
__global__ void detect_kernel(const int* __restrict__ ei, int* __restrict__ flag){
  int z = (ei[1]==0) + (ei[3]==0) + (ei[5]==0) + (ei[7]==0);
  *flag = (z == 4) ? 1 : 0;
}

// ---------- x -> bf16 ----------
__global__ void cvt_x_kernel(const float* __restrict__ x, bf16_t* __restrict__ xb, int n4){
  int t = blockIdx.x*blockDim.x + threadIdx.x;
  if (t >= n4) return;
  const float4 v = *(const float4*)(x + (size_t)t*4);
  bf16x4 o = { (bf16_t)v.x, (bf16_t)v.y, (bf16_t)v.z, (bf16_t)v.w };
  *(bf16x4*)(xb + (size_t)t*4) = o;
}

// ---------- fold W1 into Wkqv; emit TRANSPOSED bf16 WcombT[768][256] + fp32 bcomb[768] ----------
// Output column layout (KV-PACKED): cols [0,256) = q (h*128+d);
// cols [256,768): r = n-256, h = r>>8, g = (r&255)>>3, half = (r>>2)&1, dd = r&3, d = g*4+dd;
//   half 0 -> k_scaled[h][d], half 1 -> v[h][d].
__global__ void prep_weights(const float* __restrict__ Wkqv, const float* __restrict__ bkqv,
                             const float* __restrict__ W1,
                             bf16_t* __restrict__ WcombT, float* __restrict__ bcomb){
  int n = blockIdx.x * blockDim.x + threadIdx.x;   // 0..767 (output col, permuted layout)
  int c = blockIdx.y;                              // 0..256 (k index; 256 = bias)
  if (n >= 768) return;
  const float rs = rsqrtf(128.0f);
  bool isBias = (c == 256);
  const float* arow = isBias ? bkqv : (Wkqv + (size_t)c*768);
  float val;
  if (n < 256){                       // q
    int h = n >> 7, d = n & 127;
    float s = 0.f;
    for (int t = 0; t < 128; ++t)
      s = fmaf(arow[h*128 + t], W1[(size_t)(128 + t)*128 + d], s);
    val = s;
  } else {
    int r = n - 256;
    int h = r >> 8, t8 = r & 255;
    int g = t8 >> 3, half = (t8 >> 2) & 1, dd = t8 & 3;
    int d = g*4 + dd;
    if (half == 0){                   // k (scaled)
      float s = 0.f;
      for (int t = 0; t < 128; ++t)
        s = fmaf(arow[256 + h*128 + t], W1[(size_t)t*128 + d], s);
      val = s * rs;
    } else {                          // v passthrough
      val = arow[512 + h*128 + d];
    }
  }
  if (isBias) bcomb[n] = val;
  else        WcombT[(size_t)n*256 + c] = (bf16_t)val;
}

// ---------- Wout -> transposed bf16 WoutT[256][256] ----------
__global__ void prep_wout(const float* __restrict__ W, bf16_t* __restrict__ Wt){
  int t = blockIdx.x*blockDim.x + threadIdx.x;  // 65536
  int n = t & 255, c = t >> 8;
  Wt[(size_t)n*256 + c] = (bf16_t)W[(size_t)c*256 + n];
}

// ---------- degree count over the 2*E0 non-self edges (dst side) ----------
__global__ void deg_kernel(const int* __restrict__ ei, const int* __restrict__ flag,
                           int* __restrict__ deg, int E0, int Nn){
  int t = blockIdx.x*blockDim.x + threadIdx.x;
  if (t >= 2*E0) return;
  int is64 = *flag;
  int i = (t < E0) ? eidx(ei,is64,(long long)E0+t) : eidx(ei,is64,t-E0);
  i = min(max(i,0), Nn-1);
  atomicAdd(deg + i, 1);
}

// ---------- exclusive prefix scan of (deg+1) -> off[0..N] (self-loop slot included) ----------
__global__ __launch_bounds__(1024) void scan_kernel(const int* __restrict__ deg,
                                                    int* __restrict__ off, int N){
  __shared__ int wsum[16];
  __shared__ int carry_s;
  int tid = threadIdx.x, lane = tid & 63, w = tid >> 6;
  if (tid == 0) carry_s = 0;
  __syncthreads();
  for (int base = 0; base < N; base += 1024){
    int carry = carry_s;
    int v = (base + tid < N) ? (deg[base + tid] + 1) : 0;
    int incl = v;
    #pragma unroll
    for (int o = 1; o < 64; o <<= 1){
      int t = __shfl_up(incl, o, 64);
      if (lane >= o) incl += t;
    }
    if (lane == 63) wsum[w] = incl;
    __syncthreads();
    if (w == 0 && lane < 16){
      int sv = wsum[lane];
      #pragma unroll
      for (int o = 1; o < 16; o <<= 1){
        int t = __shfl_up(sv, o, 64);
        if (lane >= o) sv += t;
      }
      wsum[lane] = sv;
    }
    __syncthreads();
    int wpref = (w == 0) ? 0 : wsum[w-1];
    if (base + tid < N) off[base + tid] = carry + wpref + incl - v;
    __syncthreads();
    if (tid == 1023) carry_s = carry + wsum[15];
    __syncthreads();
  }
  if (threadIdx.x == 0) off[N] = carry_s;
}

// ---------- scatter source index j into CSR buckets (incl. self-loops) ----------
__global__ void scatter_kernel(const int* __restrict__ ei, const int* __restrict__ flag,
                               const int* __restrict__ off, int* __restrict__ cursor,
                               int* __restrict__ bj, int E0, int Nn){
  int e = blockIdx.x*blockDim.x + threadIdx.x;
  int E = 2*E0 + Nn;
  if (e >= E) return;
  int is64 = *flag;
  int j, i;
  if (e < E0){ j = eidx(ei,is64,e); i = eidx(ei,is64,(long long)E0+e); }
  else if (e < 2*E0){ int t = e - E0; i = eidx(ei,is64,t); j = eidx(ei,is64,(long long)E0+t); }
  else { i = j = e - 2*E0; }
  i = min(max(i,0), Nn-1); j = min(max(j,0), Nn-1);
  int pos = atomicAdd(cursor + i, 1);
  bj[off[i] + pos] = j;
}

// ---------- bf16 MFMA GEMM, K=256: C = A[M,256] @ Bt[N,256]^T + epilogue ----------
// T3+T4 pipeline: 3 LDS buffers, depth-2 prefetch, counted s_waitcnt vmcnt(N)
// (never drains to 0 in steady state) + raw s_barrier. Each wave keeps 8
// global_load_lds outstanding across every barrier -> HBM stays saturated;
// the old __syncthreads() vmcnt(0) drain (the 20->80% idle) is gone.
// MODE 0: C(bf16) = AB + bias[n]
// MODE 1: C(fp32) = relu(AB + (deg[m]+1)*bias[n]) + xres[m*N+n]
template<int MODE, typename OutT>
__global__ __launch_bounds__(256) void mfma_gemm(
    const bf16_t* __restrict__ A, const bf16_t* __restrict__ Bt,
    const float* __restrict__ bias, OutT* __restrict__ C,
    int M, int N,
    const int* __restrict__ deg, const float* __restrict__ xres)
{
  __shared__ bf16_t As[3][128*32];   // 8 KB each, 48 KB total -> 3 blocks/CU
  __shared__ bf16_t Bs[3][128*32];
  const int tid = threadIdx.x;
  const int wave = tid >> 6, lane = tid & 63;
  const int row16 = lane & 15, quad = lane >> 4;

  // XCD swizzle: bid%8 = XCD (dispatch round-robin heuristic); n fastest per XCD
  const int nn = N >> 7;
  const int bid = blockIdx.x;
  const int strip = bid / (8*nn);
  const int inner = bid % (8*nn);
  const int m0 = (strip*8 + (inner & 7)) * 128;
  const int n0 = (inner >> 3) * 128;
  const int wm = (wave >> 1) * 64, wn = (wave & 1) * 64;

  const int f0 = wave*2, f1 = wave*2 + 1;
  const int gm0 = min(m0 + f0*16 + row16, M-1);
  const int gm1 = min(m0 + f1*16 + row16, M-1);
  const int gn0 = n0 + f0*16 + row16;
  const int gn1 = n0 + f1*16 + row16;

  const size_t aoff0 = (size_t)gm0*256 + quad*8;
  const size_t aoff1 = (size_t)gm1*256 + quad*8;
  const size_t boff0 = (size_t)gn0*256 + quad*8;
  const size_t boff1 = (size_t)gn1*256 + quad*8;

  floatx4 acc[4][4];
  #pragma unroll
  for (int a=0;a<4;++a)
    #pragma unroll
    for (int b=0;b<4;++b) acc[a][b] = (floatx4){0.f,0.f,0.f,0.f};

  // 4 loads per wave per tile (2 A frags + 2 B frags)
  #define STAGE(kt, buf) do{ \
    async_load16(A  + aoff0 + (kt)*32, (char*)As[buf] + f0*1024); \
    async_load16(A  + aoff1 + (kt)*32, (char*)As[buf] + f1*1024); \
    async_load16(Bt + boff0 + (kt)*32, (char*)Bs[buf] + f0*1024); \
    async_load16(Bt + boff1 + (kt)*32, (char*)Bs[buf] + f1*1024); }while(0)

  // prologue: tiles 0,1 in flight (8 loads/wave outstanding)
  STAGE(0,0); STAGE(1,1);

  // Phase kt: issue tile kt+2 (overwrites buf (kt-1)%3 -- safe: phase kt-1's
  // trailing barrier proved all waves finished reading it), wait vmcnt(vm) so
  // tile kt's 4 loads (oldest in FIFO) have landed, ready-barrier, compute,
  // read-done-barrier. vm = 4*min(2, 7-kt): 8,8,8,8,8,8,4,0.
  #define PHASE(kt, vm) do{ \
    if ((kt)+2 < 8) STAGE((kt)+2, ((kt)+2)%3); \
    asm volatile("s_waitcnt vmcnt(" #vm ")" ::: "memory"); \
    __builtin_amdgcn_s_barrier(); \
    __builtin_amdgcn_sched_barrier(0); \
    bf16x8 af[4], bfr[4]; \
    _Pragma("unroll") \
    for (int t = 0; t < 4; ++t){ \
      af[t]  = *(const bf16x8*)((const char*)As[(kt)%3] + ((wm>>4)+t)*1024 + lane*16); \
      bfr[t] = *(const bf16x8*)((const char*)Bs[(kt)%3] + ((wn>>4)+t)*1024 + lane*16); \
    } \
    __builtin_amdgcn_s_setprio(1); \
    _Pragma("unroll") \
    for (int mt=0;mt<4;++mt) \
      _Pragma("unroll") \
      for (int nt=0;nt<4;++nt) \
        acc[mt][nt] = __builtin_amdgcn_mfma_f32_16x16x32_bf16(af[mt], bfr[nt], acc[mt][nt], 0,0,0); \
    __builtin_amdgcn_s_setprio(0); \
    if ((kt) < 7){ \
      asm volatile("s_waitcnt lgkmcnt(0)" ::: "memory"); \
      __builtin_amdgcn_sched_barrier(0); \
      __builtin_amdgcn_s_barrier(); \
    } }while(0)

  PHASE(0,8); PHASE(1,8); PHASE(2,8); PHASE(3,8);
  PHASE(4,8); PHASE(5,8); PHASE(6,4); PHASE(7,0);

  #undef PHASE
  #undef STAGE

  // epilogue: C/D layout col=lane&15, row=quad*4+reg
  #pragma unroll
  for (int mt=0;mt<4;++mt){
    #pragma unroll
    for (int r=0;r<4;++r){
      int m = m0 + wm + mt*16 + quad*4 + r;
      if (m >= M) continue;
      float dg = (MODE==1) ? (float)(deg[m]+1) : 0.f;
      #pragma unroll
      for (int nt=0;nt<4;++nt){
        int n = n0 + wn + nt*16 + row16;
        float v = acc[mt][nt][r];
        if (MODE == 0){
          v += bias[n];
        } else {
          v = fmaxf(v + dg*bias[n], 0.f) + xres[(size_t)m*N + n];
        }
        C[(size_t)m*N + n] = (OutT)v;
      }
    }
  }
}

// ---------- fused attention: score + online softmax + aggregate, one wave per node ----------
// P layout: [0,256) q; [256,768) kv-packed: head h at 256+h*256, group g holds
// k[g*4..g*4+3] then v[g*4..g*4+3] -> ONE bf16x8 load per edge per lane.
__global__ __launch_bounds__(256) void fused_attn_kernel(
    const bf16_t* __restrict__ P, const int* __restrict__ bj, const int* __restrict__ off,
    const float* __restrict__ b1, const float* __restrict__ W2, const float* __restrict__ b2,
    bf16_t* __restrict__ aggb, int Nn)
{
  int i = blockIdx.x * (blockDim.x >> 6) + (threadIdx.x >> 6);
  if (i >= Nn) return;
  int lane = threadIdx.x & 63;
  int h = lane >> 5, g = lane & 31, d = g * 4;

  const float4 qv  = cvt4(*(const bf16x4*)(P + (size_t)i*768 + h*128 + d));
  const float4 b1v = *(const float4*)(b1 + d);
  const float4 w2v = *(const float4*)(W2 + d);
  const float b2v  = b2[0];

  float m = -3.0e38f, s = 0.f;
  float4 acc = make_float4(0.f,0.f,0.f,0.f);
  int s0 = off[i], s1 = off[i+1];
  for (int t = s0; t < s1; ++t){
    int j = bj[t];
    bf16x8 kvv = *(const bf16x8*)(P + (size_t)j*768 + 256 + h*256 + g*8);
    float kx = (float)kvv[0], ky = (float)kvv[1], kz = (float)kvv[2], kw = (float)kvv[3];
    float vx = (float)kvv[4], vy = (float)kvv[5], vz = (float)kvv[6], vw = (float)kvv[7];
    float p = fmaxf(qv.x+kx+b1v.x, 0.f)*w2v.x
            + fmaxf(qv.y+ky+b1v.y, 0.f)*w2v.y
            + fmaxf(qv.z+kz+b1v.z, 0.f)*w2v.z
            + fmaxf(qv.w+kw+b1v.w, 0.f)*w2v.w;
    // reduce across the 32-lane half-wave (bit5 = head, untouched)
    #pragma unroll
    for (int o = 16; o >= 1; o >>= 1)
      p += __shfl_xor(p, o, 64);
    float a = p + b2v;
    float mn = fmaxf(m, a);
    float sc = __expf(m - mn);
    float e  = __expf(a - mn);
    s = s*sc + e;
    acc.x = fmaf(acc.x, sc, e*vx);
    acc.y = fmaf(acc.y, sc, e*vy);
    acc.z = fmaf(acc.z, sc, e*vz);
    acc.w = fmaf(acc.w, sc, e*vw);
    m = mn;
  }
  float inv = 1.f / (s + 1e-16f);
  bf16x4 ob = { (bf16_t)(acc.x*inv), (bf16_t)(acc.y*inv), (bf16_t)(acc.z*inv), (bf16_t)(acc.w*inv) };
  *(bf16x4*)(aggb + (size_t)i*256 + h*128 + d) = ob;
}

// ---------- launch ----------
extern "C" void kernel_launch(void* const* d_in, const int* in_sizes, int n_in,
                              void* d_out, int out_size, void* d_ws, size_t ws_size,
                              hipStream_t stream)
{
  const float* x     = (const float*)d_in[0];
  const int*   ei    = (const int*)d_in[1];
  const float* Wkqv  = (const float*)d_in[2];
  const float* bkqv  = (const float*)d_in[3];
  const float* W1    = (const float*)d_in[4];
  const float* b1    = (const float*)d_in[5];
  const float* W2    = (const float*)d_in[6];
  const float* b2    = (const float*)d_in[7];
  const float* Wout  = (const float*)d_in[8];
  const float* bout  = (const float*)d_in[9];
  float* out = (float*)d_out;

  const int N  = in_sizes[0] / EMB;   // 50000
  const int E0 = in_sizes[1] / 2;     // 100000
  const int E  = 2*E0 + N;            // 250000

  // workspace layout (fp32-word offsets; all 16B-aligned)
  float* base = (float*)d_ws;
  bf16_t* WcombT = (bf16_t*)base;                       // 768*256 bf16
  float*  bcomb  = base + 98304;                        // 768 w
  bf16_t* WoutT  = (bf16_t*)(base + 98304 + 768);       // 256*256 bf16
  bf16_t* xb     = (bf16_t*)(base + 131840);            // N*256 bf16
  bf16_t* Pb     = (bf16_t*)(base + 131840 + 6400000);  // N*768 bf16
  bf16_t* aggb   = (bf16_t*)(Pb + (size_t)N*768);       // N*256 bf16
  int* deg       = (int*)(aggb + (size_t)N*256);        // N
  int* cursor    = deg + N;                             // N
  int* flag      = cursor + N;                          // 1
  int* off       = flag + 1;                            // N+1
  int* bj        = off + (N+1);                         // E

  hipMemsetAsync(deg, 0, (size_t)2*N*sizeof(int), stream);  // deg + cursor

  detect_kernel<<<1,1,0,stream>>>(ei, flag);
  cvt_x_kernel<<<((N*EMB/4)+255)/256,256,0,stream>>>(x, xb, N*EMB/4);
  prep_weights<<<dim3(3,257),256,0,stream>>>(Wkqv, bkqv, W1, WcombT, bcomb);
  prep_wout<<<256,256,0,stream>>>(Wout, WoutT);

  deg_kernel<<<(2*E0+255)/256,256,0,stream>>>(ei, flag, deg, E0, N);
  scan_kernel<<<1,1024,0,stream>>>(deg, off, N);
  scatter_kernel<<<(E+255)/256,256,0,stream>>>(ei, flag, off, cursor, bj, E0, N);

  const int nm8 = (((N+127)/128) + 7) & ~7;   // m-strips padded to multiple of 8
  mfma_gemm<0, bf16_t><<<nm8*6,256,0,stream>>>(xb, WcombT, bcomb, Pb, N, 768, nullptr, nullptr);
  fused_attn_kernel<<<(N+3)/4,256,0,stream>>>(Pb, bj, off, b1, W2, b2, aggb, N);
  mfma_gemm<1, float><<<nm8*2,256,0,stream>>>(aggb, WoutT, bout, out, N, 256, deg, x);
}

// Round 3
// 339.832 us; speedup vs baseline: 1.1181x; 1.0114x over previous
//
#include <hip/hip_runtime.h>
#include <hip/hip_bf16.h>

#define EMB 256

typedef __bf16 bf16_t;
typedef __attribute__((ext_vector_type(8))) __bf16 bf16x8;
typedef __attribute__((ext_vector_type(4))) __bf16 bf16x4;
typedef __attribute__((ext_vector_type(4))) float floatx4;

// ---------- helpers ----------
__device__ __forceinline__ int eidx(const int* __restrict__ p, int is64, long long k){
  return is64 ? p[2*k] : p[(int)k];
}
// async global->LDS, 16B per lane; LDS base must be WAVE-UNIFORM, lands at base + lane*16
__device__ __forceinline__ void async_load16(const void* g, void* l){
  __builtin_amdgcn_global_load_lds(
      (const __attribute__((address_space(1))) unsigned int*)g,
      (__attribute__((address_space(3))) unsigned int*)l,
      16, 0, 0);
}
__device__ __forceinline__ float4 cvt4(bf16x4 v){
  return make_float4((float)v.x, (float)v.y, (float)v.z, (float)v.w);
}

// ---------- dtype detect ----------
__global__ void detect_kernel(const int* __restrict__ ei, int* __restrict__ flag){
  int z = (ei[1]==0) + (ei[3]==0) + (ei[5]==0) + (ei[7]==0);
  *flag = (z == 4) ? 1 : 0;
}

// ---------- x -> bf16 ----------
__global__ void cvt_x_kernel(const float* __restrict__ x, bf16_t* __restrict__ xb, int n4){
  int t = blockIdx.x*blockDim.x + threadIdx.x;
  if (t >= n4) return;
  const float4 v = *(const float4*)(x + (size_t)t*4);
  bf16x4 o = { (bf16_t)v.x, (bf16_t)v.y, (bf16_t)v.z, (bf16_t)v.w };
  *(bf16x4*)(xb + (size_t)t*4) = o;
}

// ---------- fold W1 into Wkqv; emit TRANSPOSED bf16 WcombT[768][256] + fp32 bcomb[768] ----------
// Output column layout (KV-PACKED): cols [0,256) = q (h*128+d);
// cols [256,768): r = n-256, h = r>>8, g = (r&255)>>3, half = (r>>2)&1, dd = r&3, d = g*4+dd;
//   half 0 -> k_scaled[h][d], half 1 -> v[h][d].
__global__ void prep_weights(const float* __restrict__ Wkqv, const float* __restrict__ bkqv,
                             const float* __restrict__ W1,
                             bf16_t* __restrict__ WcombT, float* __restrict__ bcomb){
  int n = blockIdx.x * blockDim.x + threadIdx.x;   // 0..767 (output col, permuted layout)
  int c = blockIdx.y;                              // 0..256 (k index; 256 = bias)
  if (n >= 768) return;
  const float rs = rsqrtf(128.0f);
  bool isBias = (c == 256);
  const float* arow = isBias ? bkqv : (Wkqv + (size_t)c*768);
  float val;
  if (n < 256){                       // q
    int h = n >> 7, d = n & 127;
    float s = 0.f;
    for (int t = 0; t < 128; ++t)
      s = fmaf(arow[h*128 + t], W1[(size_t)(128 + t)*128 + d], s);
    val = s;
  } else {
    int r = n - 256;
    int h = r >> 8, t8 = r & 255;
    int g = t8 >> 3, half = (t8 >> 2) & 1, dd = t8 & 3;
    int d = g*4 + dd;
    if (half == 0){                   // k (scaled)
      float s = 0.f;
      for (int t = 0; t < 128; ++t)
        s = fmaf(arow[256 + h*128 + t], W1[(size_t)t*128 + d], s);
      val = s * rs;
    } else {                          // v passthrough
      val = arow[512 + h*128 + d];
    }
  }
  if (isBias) bcomb[n] = val;
  else        WcombT[(size_t)n*256 + c] = (bf16_t)val;
}

// ---------- Wout -> transposed bf16 WoutT[256][256] ----------
__global__ void prep_wout(const float* __restrict__ W, bf16_t* __restrict__ Wt){
  int t = blockIdx.x*blockDim.x + threadIdx.x;  // 65536
  int n = t & 255, c = t >> 8;
  Wt[(size_t)n*256 + c] = (bf16_t)W[(size_t)c*256 + n];
}

// ---------- degree count over the 2*E0 non-self edges (dst side) ----------
__global__ void deg_kernel(const int* __restrict__ ei, const int* __restrict__ flag,
                           int* __restrict__ deg, int E0, int Nn){
  int t = blockIdx.x*blockDim.x + threadIdx.x;
  if (t >= 2*E0) return;
  int is64 = *flag;
  int i = (t < E0) ? eidx(ei,is64,(long long)E0+t) : eidx(ei,is64,t-E0);
  i = min(max(i,0), Nn-1);
  atomicAdd(deg + i, 1);
}

// ---------- exclusive prefix scan of (deg+1) -> off[0..N] (self-loop slot included) ----------
__global__ __launch_bounds__(1024) void scan_kernel(const int* __restrict__ deg,
                                                    int* __restrict__ off, int N){
  __shared__ int wsum[16];
  __shared__ int carry_s;
  int tid = threadIdx.x, lane = tid & 63, w = tid >> 6;
  if (tid == 0) carry_s = 0;
  __syncthreads();
  for (int base = 0; base < N; base += 1024){
    int carry = carry_s;
    int v = (base + tid < N) ? (deg[base + tid] + 1) : 0;
    int incl = v;
    #pragma unroll
    for (int o = 1; o < 64; o <<= 1){
      int t = __shfl_up(incl, o, 64);
      if (lane >= o) incl += t;
    }
    if (lane == 63) wsum[w] = incl;
    __syncthreads();
    if (w == 0 && lane < 16){
      int sv = wsum[lane];
      #pragma unroll
      for (int o = 1; o < 16; o <<= 1){
        int t = __shfl_up(sv, o, 64);
        if (lane >= o) sv += t;
      }
      wsum[lane] = sv;
    }
    __syncthreads();
    int wpref = (w == 0) ? 0 : wsum[w-1];
    if (base + tid < N) off[base + tid] = carry + wpref + incl - v;
    __syncthreads();
    if (tid == 1023) carry_s = carry + wsum[15];
    __syncthreads();
  }
  if (threadIdx.x == 0) off[N] = carry_s;
}

// ---------- scatter source index j into CSR buckets (incl. self-loops) ----------
__global__ void scatter_kernel(const int* __restrict__ ei, const int* __restrict__ flag,
                               const int* __restrict__ off, int* __restrict__ cursor,
                               int* __restrict__ bj, int E0, int Nn){
  int e = blockIdx.x*blockDim.x + threadIdx.x;
  int E = 2*E0 + Nn;
  if (e >= E) return;
  int is64 = *flag;
  int j, i;
  if (e < E0){ j = eidx(ei,is64,e); i = eidx(ei,is64,(long long)E0+e); }
  else if (e < 2*E0){ int t = e - E0; i = eidx(ei,is64,t); j = eidx(ei,is64,(long long)E0+t); }
  else { i = j = e - 2*E0; }
  i = min(max(i,0), Nn-1); j = min(max(j,0), Nn-1);
  int pos = atomicAdd(cursor + i, 1);
  bj[off[i] + pos] = j;
}

// ---------- bf16 MFMA GEMM, K=256: C = A[M,256] @ Bt[N,256]^T + epilogue ----------
// Round-0 pipeline (best measured): double-buffered LDS, all-async staging.
// NEW: SWAPPED MFMA OPERANDS -- mfma(bfr, af) gives D[row=n_local=quad*4+r,
// col=m_local=lane&15], so each lane holds 4 CONSECUTIVE n for one m.
// Epilogue becomes 16x 8B bf16x4 stores (MODE 0) / 16x 16B float4 stores with
// float4 xres/bias loads (MODE 1), replacing 64 scalar 2B/4B accesses.
// MODE 0: C(bf16) = AB + bias[n]
// MODE 1: C(fp32) = relu(AB + (deg[m]+1)*bias[n]) + xres[m*N+n]
template<int MODE, typename OutT>
__global__ __launch_bounds__(256) void mfma_gemm(
    const bf16_t* __restrict__ A, const bf16_t* __restrict__ Bt,
    const float* __restrict__ bias, OutT* __restrict__ C,
    int M, int N,
    const int* __restrict__ deg, const float* __restrict__ xres)
{
  __shared__ bf16_t As[2][128*32];   // 8 KB each
  __shared__ bf16_t Bs[2][128*32];
  const int tid = threadIdx.x;
  const int wave = tid >> 6, lane = tid & 63;
  const int row16 = lane & 15, quad = lane >> 4;

  // XCD swizzle: bid%8 = XCD (dispatch round-robin heuristic); n fastest per XCD
  const int nn = N >> 7;
  const int bid = blockIdx.x;
  const int strip = bid / (8*nn);
  const int inner = bid % (8*nn);
  const int m0 = (strip*8 + (inner & 7)) * 128;
  const int n0 = (inner >> 3) * 128;
  const int wm = (wave >> 1) * 64, wn = (wave & 1) * 64;

  const int f0 = wave*2, f1 = wave*2 + 1;
  const int gm0 = min(m0 + f0*16 + row16, M-1);
  const int gm1 = min(m0 + f1*16 + row16, M-1);
  const int gn0 = n0 + f0*16 + row16;
  const int gn1 = n0 + f1*16 + row16;

  // prologue: stage k-tile 0 into buffer 0
  async_load16(A  + (size_t)gm0*256 + quad*8, (char*)As[0] + f0*1024);
  async_load16(A  + (size_t)gm1*256 + quad*8, (char*)As[0] + f1*1024);
  async_load16(Bt + (size_t)gn0*256 + quad*8, (char*)Bs[0] + f0*1024);
  async_load16(Bt + (size_t)gn1*256 + quad*8, (char*)Bs[0] + f1*1024);

  floatx4 acc[4][4];
  #pragma unroll
  for (int a=0;a<4;++a)
    #pragma unroll
    for (int b=0;b<4;++b) acc[a][b] = (floatx4){0.f,0.f,0.f,0.f};

  #pragma unroll
  for (int kt = 0; kt < 8; ++kt){
    const int cur = kt & 1, nxt = cur ^ 1;
    const int k1 = (kt+1)*32;

    __syncthreads();   // buffer[cur] staged; buffer[nxt] free

    if (kt < 7){
      async_load16(A  + (size_t)gm0*256 + k1 + quad*8, (char*)As[nxt] + f0*1024);
      async_load16(A  + (size_t)gm1*256 + k1 + quad*8, (char*)As[nxt] + f1*1024);
      async_load16(Bt + (size_t)gn0*256 + k1 + quad*8, (char*)Bs[nxt] + f0*1024);
      async_load16(Bt + (size_t)gn1*256 + k1 + quad*8, (char*)Bs[nxt] + f1*1024);
    }

    bf16x8 af[4], bfr[4];
    #pragma unroll
    for (int t = 0; t < 4; ++t){
      af[t]  = *(const bf16x8*)((const char*)As[cur] + ((wm>>4)+t)*1024 + lane*16);
      bfr[t] = *(const bf16x8*)((const char*)Bs[cur] + ((wn>>4)+t)*1024 + lane*16);
    }
    // SWAPPED operands: D tile gets row=n_local, col=m_local
    #pragma unroll
    for (int mt=0;mt<4;++mt)
      #pragma unroll
      for (int nt=0;nt<4;++nt)
        acc[mt][nt] = __builtin_amdgcn_mfma_f32_16x16x32_bf16(bfr[nt], af[mt], acc[mt][nt], 0,0,0);
  }

  // epilogue: per tile, lane holds m = lane&15 and n = quad*4 + {0..3} -> vector stores
  float4 b4[4];
  #pragma unroll
  for (int nt=0;nt<4;++nt)
    b4[nt] = *(const float4*)(bias + n0 + wn + nt*16 + quad*4);

  #pragma unroll
  for (int mt=0;mt<4;++mt){
    const int m = m0 + wm + mt*16 + row16;
    if (m >= M) continue;
    const float dg = (MODE==1) ? (float)(deg[m]+1) : 0.f;
    #pragma unroll
    for (int nt=0;nt<4;++nt){
      const int nb = n0 + wn + nt*16 + quad*4;
      if (MODE == 0){
        bf16x4 o = { (bf16_t)(acc[mt][nt][0] + b4[nt].x),
                     (bf16_t)(acc[mt][nt][1] + b4[nt].y),
                     (bf16_t)(acc[mt][nt][2] + b4[nt].z),
                     (bf16_t)(acc[mt][nt][3] + b4[nt].w) };
        *(bf16x4*)((bf16_t*)C + (size_t)m*N + nb) = o;
      } else {
        const float4 xr = *(const float4*)(xres + (size_t)m*N + nb);
        float4 o;
        o.x = fmaxf(acc[mt][nt][0] + dg*b4[nt].x, 0.f) + xr.x;
        o.y = fmaxf(acc[mt][nt][1] + dg*b4[nt].y, 0.f) + xr.y;
        o.z = fmaxf(acc[mt][nt][2] + dg*b4[nt].z, 0.f) + xr.z;
        o.w = fmaxf(acc[mt][nt][3] + dg*b4[nt].w, 0.f) + xr.w;
        *(float4*)((float*)C + (size_t)m*N + nb) = o;
      }
    }
  }
}

// ---------- fused attention: score + online softmax + aggregate, one wave per node ----------
// P layout: [0,256) q; [256,768) kv-packed: head h at 256+h*256, group g holds
// k[g*4..g*4+3] then v[g*4..g*4+3] -> ONE bf16x8 load per edge per lane.
__global__ __launch_bounds__(256) void fused_attn_kernel(
    const bf16_t* __restrict__ P, const int* __restrict__ bj, const int* __restrict__ off,
    const float* __restrict__ b1, const float* __restrict__ W2, const float* __restrict__ b2,
    bf16_t* __restrict__ aggb, int Nn)
{
  int i = blockIdx.x * (blockDim.x >> 6) + (threadIdx.x >> 6);
  if (i >= Nn) return;
  int lane = threadIdx.x & 63;
  int h = lane >> 5, g = lane & 31, d = g * 4;

  const float4 qv  = cvt4(*(const bf16x4*)(P + (size_t)i*768 + h*128 + d));
  const float4 b1v = *(const float4*)(b1 + d);
  const float4 w2v = *(const float4*)(W2 + d);
  const float b2v  = b2[0];

  float m = -3.0e38f, s = 0.f;
  float4 acc = make_float4(0.f,0.f,0.f,0.f);
  int s0 = off[i], s1 = off[i+1];
  for (int t = s0; t < s1; ++t){
    int j = bj[t];
    bf16x8 kvv = *(const bf16x8*)(P + (size_t)j*768 + 256 + h*256 + g*8);
    float kx = (float)kvv[0], ky = (float)kvv[1], kz = (float)kvv[2], kw = (float)kvv[3];
    float vx = (float)kvv[4], vy = (float)kvv[5], vz = (float)kvv[6], vw = (float)kvv[7];
    float p = fmaxf(qv.x+kx+b1v.x, 0.f)*w2v.x
            + fmaxf(qv.y+ky+b1v.y, 0.f)*w2v.y
            + fmaxf(qv.z+kz+b1v.z, 0.f)*w2v.z
            + fmaxf(qv.w+kw+b1v.w, 0.f)*w2v.w;
    // reduce across the 32-lane half-wave (bit5 = head, untouched)
    #pragma unroll
    for (int o = 16; o >= 1; o >>= 1)
      p += __shfl_xor(p, o, 64);
    float a = p + b2v;
    float mn = fmaxf(m, a);
    float sc = __expf(m - mn);
    float e  = __expf(a - mn);
    s = s*sc + e;
    acc.x = fmaf(acc.x, sc, e*vx);
    acc.y = fmaf(acc.y, sc, e*vy);
    acc.z = fmaf(acc.z, sc, e*vz);
    acc.w = fmaf(acc.w, sc, e*vw);
    m = mn;
  }
  float inv = 1.f / (s + 1e-16f);
  bf16x4 ob = { (bf16_t)(acc.x*inv), (bf16_t)(acc.y*inv), (bf16_t)(acc.z*inv), (bf16_t)(acc.w*inv) };
  *(bf16x4*)(aggb + (size_t)i*256 + h*128 + d) = ob;
}

// ---------- launch ----------
extern "C" void kernel_launch(void* const* d_in, const int* in_sizes, int n_in,
                              void* d_out, int out_size, void* d_ws, size_t ws_size,
                              hipStream_t stream)
{
  const float* x     = (const float*)d_in[0];
  const int*   ei    = (const int*)d_in[1];
  const float* Wkqv  = (const float*)d_in[2];
  const float* bkqv  = (const float*)d_in[3];
  const float* W1    = (const float*)d_in[4];
  const float* b1    = (const float*)d_in[5];
  const float* W2    = (const float*)d_in[6];
  const float* b2    = (const float*)d_in[7];
  const float* Wout  = (const float*)d_in[8];
  const float* bout  = (const float*)d_in[9];
  float* out = (float*)d_out;

  const int N  = in_sizes[0] / EMB;   // 50000
  const int E0 = in_sizes[1] / 2;     // 100000
  const int E  = 2*E0 + N;            // 250000

  // workspace layout (fp32-word offsets; all 16B-aligned)
  float* base = (float*)d_ws;
  bf16_t* WcombT = (bf16_t*)base;                       // 768*256 bf16
  float*  bcomb  = base + 98304;                        // 768 w
  bf16_t* WoutT  = (bf16_t*)(base + 98304 + 768);       // 256*256 bf16
  bf16_t* xb     = (bf16_t*)(base + 131840);            // N*256 bf16
  bf16_t* Pb     = (bf16_t*)(base + 131840 + 6400000);  // N*768 bf16
  bf16_t* aggb   = (bf16_t*)(Pb + (size_t)N*768);       // N*256 bf16
  int* deg       = (int*)(aggb + (size_t)N*256);        // N
  int* cursor    = deg + N;                             // N
  int* flag      = cursor + N;                          // 1
  int* off       = flag + 1;                            // N+1
  int* bj        = off + (N+1);                         // E

  hipMemsetAsync(deg, 0, (size_t)2*N*sizeof(int), stream);  // deg + cursor

  detect_kernel<<<1,1,0,stream>>>(ei, flag);
  cvt_x_kernel<<<((N*EMB/4)+255)/256,256,0,stream>>>(x, xb, N*EMB/4);
  prep_weights<<<dim3(3,257),256,0,stream>>>(Wkqv, bkqv, W1, WcombT, bcomb);
  prep_wout<<<256,256,0,stream>>>(Wout, WoutT);

  deg_kernel<<<(2*E0+255)/256,256,0,stream>>>(ei, flag, deg, E0, N);
  scan_kernel<<<1,1024,0,stream>>>(deg, off, N);
  scatter_kernel<<<(E+255)/256,256,0,stream>>>(ei, flag, off, cursor, bj, E0, N);

  const int nm8 = (((N+127)/128) + 7) & ~7;   // m-strips padded to multiple of 8
  mfma_gemm<0, bf16_t><<<nm8*6,256,0,stream>>>(xb, WcombT, bcomb, Pb, N, 768, nullptr, nullptr);
  fused_attn_kernel<<<(N+3)/4,256,0,stream>>>(Pb, bj, off, b1, W2, b2, aggb, N);
  mfma_gemm<1, float><<<nm8*2,256,0,stream>>>(aggb, WoutT, bout, out, N, 256, deg, x);
}

// Round 4
// 293.018 us; speedup vs baseline: 1.2968x; 1.1598x over previous
//
#include <hip/hip_runtime.h>
#include <hip/hip_bf16.h>

#define EMB 256

typedef __bf16 bf16_t;
typedef __attribute__((ext_vector_type(8))) __bf16 bf16x8;
typedef __attribute__((ext_vector_type(4))) __bf16 bf16x4;
typedef __attribute__((ext_vector_type(4))) float floatx4;

// ---------- helpers ----------
__device__ __forceinline__ int eidx(const int* __restrict__ p, int is64, long long k){
  return is64 ? p[2*k] : p[(int)k];
}
// async global->LDS, 16B per lane; LDS base must be WAVE-UNIFORM, lands at base + lane*16
__device__ __forceinline__ void async_load16(const void* g, void* l){
  __builtin_amdgcn_global_load_lds(
      (const __attribute__((address_space(1))) unsigned int*)g,
      (__attribute__((address_space(3))) unsigned int*)l,
      16, 0, 0);
}
__device__ __forceinline__ float4 cvt4(bf16x4 v){
  return make_float4((float)v.x, (float)v.y, (float)v.z, (float)v.w);
}

// ---------- dtype detect ----------
__global__ void detect_kernel(const int* __restrict__ ei, int* __restrict__ flag){
  int z = (ei[1]==0) + (ei[3]==0) + (ei[5]==0) + (ei[7]==0);
  *flag = (z == 4) ? 1 : 0;
}

// ---------- x -> bf16 ----------
__global__ void cvt_x_kernel(const float* __restrict__ x, bf16_t* __restrict__ xb, int n4){
  int t = blockIdx.x*blockDim.x + threadIdx.x;
  if (t >= n4) return;
  const float4 v = *(const float4*)(x + (size_t)t*4);
  bf16x4 o = { (bf16_t)v.x, (bf16_t)v.y, (bf16_t)v.z, (bf16_t)v.w };
  *(bf16x4*)(xb + (size_t)t*4) = o;
}

// ---------- fold W1 into Wkqv; emit TRANSPOSED bf16 WcombT[768][256] + fp32 bcomb[768] ----------
// Output column layout (KV-PACKED): cols [0,256) = q (h*128+d);
// cols [256,768): r = n-256, h = r>>8, g = (r&255)>>3, half = (r>>2)&1, dd = r&3, d = g*4+dd;
//   half 0 -> k_scaled[h][d], half 1 -> v[h][d].
__global__ void prep_weights(const float* __restrict__ Wkqv, const float* __restrict__ bkqv,
                             const float* __restrict__ W1,
                             bf16_t* __restrict__ WcombT, float* __restrict__ bcomb){
  int n = blockIdx.x * blockDim.x + threadIdx.x;   // 0..767 (output col, permuted layout)
  int c = blockIdx.y;                              // 0..256 (k index; 256 = bias)
  if (n >= 768) return;
  const float rs = rsqrtf(128.0f);
  bool isBias = (c == 256);
  const float* arow = isBias ? bkqv : (Wkqv + (size_t)c*768);
  float val;
  if (n < 256){                       // q
    int h = n >> 7, d = n & 127;
    float s = 0.f;
    for (int t = 0; t < 128; ++t)
      s = fmaf(arow[h*128 + t], W1[(size_t)(128 + t)*128 + d], s);
    val = s;
  } else {
    int r = n - 256;
    int h = r >> 8, t8 = r & 255;
    int g = t8 >> 3, half = (t8 >> 2) & 1, dd = t8 & 3;
    int d = g*4 + dd;
    if (half == 0){                   // k (scaled)
      float s = 0.f;
      for (int t = 0; t < 128; ++t)
        s = fmaf(arow[256 + h*128 + t], W1[(size_t)t*128 + d], s);
      val = s * rs;
    } else {                          // v passthrough
      val = arow[512 + h*128 + d];
    }
  }
  if (isBias) bcomb[n] = val;
  else        WcombT[(size_t)n*256 + c] = (bf16_t)val;
}

// ---------- Wout -> transposed bf16 WoutT[256][256] ----------
__global__ void prep_wout(const float* __restrict__ W, bf16_t* __restrict__ Wt){
  int t = blockIdx.x*blockDim.x + threadIdx.x;  // 65536
  int n = t & 255, c = t >> 8;
  Wt[(size_t)n*256 + c] = (bf16_t)W[(size_t)c*256 + n];
}

// ---------- degree count over the 2*E0 non-self edges (dst side) ----------
__global__ void deg_kernel(const int* __restrict__ ei, const int* __restrict__ flag,
                           int* __restrict__ deg, int E0, int Nn){
  int t = blockIdx.x*blockDim.x + threadIdx.x;
  if (t >= 2*E0) return;
  int is64 = *flag;
  int i = (t < E0) ? eidx(ei,is64,(long long)E0+t) : eidx(ei,is64,t-E0);
  i = min(max(i,0), Nn-1);
  atomicAdd(deg + i, 1);
}

// ---------- hierarchical exclusive scan of (deg+1) -> off[0..N] ----------
// scan1: per-block (1024) local exclusive scan + block sums
__global__ __launch_bounds__(1024) void scan1_kernel(const int* __restrict__ deg,
                                                     int* __restrict__ off,
                                                     int* __restrict__ bsum, int N){
  __shared__ int wsum[16];
  int tid = threadIdx.x, lane = tid & 63, w = tid >> 6;
  int i = blockIdx.x*1024 + tid;
  int v = (i < N) ? (deg[i] + 1) : 0;
  int incl = v;
  #pragma unroll
  for (int o = 1; o < 64; o <<= 1){
    int t = __shfl_up(incl, o, 64);
    if (lane >= o) incl += t;
  }
  if (lane == 63) wsum[w] = incl;
  __syncthreads();
  if (w == 0 && lane < 16){
    int sv = wsum[lane];
    #pragma unroll
    for (int o = 1; o < 16; o <<= 1){
      int t = __shfl_up(sv, o, 64);
      if (lane >= o) sv += t;
    }
    wsum[lane] = sv;
  }
  __syncthreads();
  int wpref = (w == 0) ? 0 : wsum[w-1];
  if (i < N) off[i] = wpref + incl - v;          // block-local exclusive
  if (tid == 1023) bsum[blockIdx.x] = wpref + incl;  // block total
}

// scan2: single block scans bsum[nb] (nb<=1024) in place -> exclusive; writes grand total to off[N]
__global__ __launch_bounds__(1024) void scan2_kernel(int* __restrict__ bsum,
                                                     int* __restrict__ off, int nb, int N){
  __shared__ int wsum[16];
  int tid = threadIdx.x, lane = tid & 63, w = tid >> 6;
  int v = (tid < nb) ? bsum[tid] : 0;
  int incl = v;
  #pragma unroll
  for (int o = 1; o < 64; o <<= 1){
    int t = __shfl_up(incl, o, 64);
    if (lane >= o) incl += t;
  }
  if (lane == 63) wsum[w] = incl;
  __syncthreads();
  if (w == 0 && lane < 16){
    int sv = wsum[lane];
    #pragma unroll
    for (int o = 1; o < 16; o <<= 1){
      int t = __shfl_up(sv, o, 64);
      if (lane >= o) sv += t;
    }
    wsum[lane] = sv;
  }
  __syncthreads();
  int wpref = (w == 0) ? 0 : wsum[w-1];
  if (tid < nb) bsum[tid] = wpref + incl - v;    // exclusive block offsets
  if (tid == 1023) off[N] = wpref + incl;        // grand total
}

// scan3: add block offsets
__global__ void scan3_kernel(int* __restrict__ off, const int* __restrict__ bsum, int N){
  int i = blockIdx.x*256 + threadIdx.x;
  if (i < N) off[i] += bsum[i >> 10];
}

// ---------- scatter source index j into CSR buckets (incl. self-loops) ----------
__global__ void scatter_kernel(const int* __restrict__ ei, const int* __restrict__ flag,
                               const int* __restrict__ off, int* __restrict__ cursor,
                               int* __restrict__ bj, int E0, int Nn){
  int e = blockIdx.x*blockDim.x + threadIdx.x;
  int E = 2*E0 + Nn;
  if (e >= E) return;
  int is64 = *flag;
  int j, i;
  if (e < E0){ j = eidx(ei,is64,e); i = eidx(ei,is64,(long long)E0+e); }
  else if (e < 2*E0){ int t = e - E0; i = eidx(ei,is64,t); j = eidx(ei,is64,(long long)E0+t); }
  else { i = j = e - 2*E0; }
  i = min(max(i,0), Nn-1); j = min(max(j,0), Nn-1);
  int pos = atomicAdd(cursor + i, 1);
  bj[off[i] + pos] = j;
}

// ---------- bf16 MFMA GEMM, K=256: C = A[M,256] @ Bt[N,256]^T + epilogue ----------
// Double-buffered all-async staging; SWAPPED MFMA OPERANDS (D row=n_local,
// col=m_local) -> per-lane 4 consecutive n => vectorized epilogue.
// MODE 0: C(bf16) = AB + bias[n]
// MODE 1: C(fp32) = relu(AB + (deg[m]+1)*bias[n]) + xres[m*N+n]
template<int MODE, typename OutT>
__global__ __launch_bounds__(256) void mfma_gemm(
    const bf16_t* __restrict__ A, const bf16_t* __restrict__ Bt,
    const float* __restrict__ bias, OutT* __restrict__ C,
    int M, int N,
    const int* __restrict__ deg, const float* __restrict__ xres)
{
  __shared__ bf16_t As[2][128*32];   // 8 KB each
  __shared__ bf16_t Bs[2][128*32];
  const int tid = threadIdx.x;
  const int wave = tid >> 6, lane = tid & 63;
  const int row16 = lane & 15, quad = lane >> 4;

  // XCD swizzle: bid%8 = XCD (dispatch round-robin heuristic); n fastest per XCD
  const int nn = N >> 7;
  const int bid = blockIdx.x;
  const int strip = bid / (8*nn);
  const int inner = bid % (8*nn);
  const int m0 = (strip*8 + (inner & 7)) * 128;
  const int n0 = (inner >> 3) * 128;
  const int wm = (wave >> 1) * 64, wn = (wave & 1) * 64;

  const int f0 = wave*2, f1 = wave*2 + 1;
  const int gm0 = min(m0 + f0*16 + row16, M-1);
  const int gm1 = min(m0 + f1*16 + row16, M-1);
  const int gn0 = n0 + f0*16 + row16;
  const int gn1 = n0 + f1*16 + row16;

  // prologue: stage k-tile 0 into buffer 0
  async_load16(A  + (size_t)gm0*256 + quad*8, (char*)As[0] + f0*1024);
  async_load16(A  + (size_t)gm1*256 + quad*8, (char*)As[0] + f1*1024);
  async_load16(Bt + (size_t)gn0*256 + quad*8, (char*)Bs[0] + f0*1024);
  async_load16(Bt + (size_t)gn1*256 + quad*8, (char*)Bs[0] + f1*1024);

  floatx4 acc[4][4];
  #pragma unroll
  for (int a=0;a<4;++a)
    #pragma unroll
    for (int b=0;b<4;++b) acc[a][b] = (floatx4){0.f,0.f,0.f,0.f};

  #pragma unroll
  for (int kt = 0; kt < 8; ++kt){
    const int cur = kt & 1, nxt = cur ^ 1;
    const int k1 = (kt+1)*32;

    __syncthreads();   // buffer[cur] staged; buffer[nxt] free

    if (kt < 7){
      async_load16(A  + (size_t)gm0*256 + k1 + quad*8, (char*)As[nxt] + f0*1024);
      async_load16(A  + (size_t)gm1*256 + k1 + quad*8, (char*)As[nxt] + f1*1024);
      async_load16(Bt + (size_t)gn0*256 + k1 + quad*8, (char*)Bs[nxt] + f0*1024);
      async_load16(Bt + (size_t)gn1*256 + k1 + quad*8, (char*)Bs[nxt] + f1*1024);
    }

    bf16x8 af[4], bfr[4];
    #pragma unroll
    for (int t = 0; t < 4; ++t){
      af[t]  = *(const bf16x8*)((const char*)As[cur] + ((wm>>4)+t)*1024 + lane*16);
      bfr[t] = *(const bf16x8*)((const char*)Bs[cur] + ((wn>>4)+t)*1024 + lane*16);
    }
    // SWAPPED operands: D tile gets row=n_local, col=m_local
    #pragma unroll
    for (int mt=0;mt<4;++mt)
      #pragma unroll
      for (int nt=0;nt<4;++nt)
        acc[mt][nt] = __builtin_amdgcn_mfma_f32_16x16x32_bf16(bfr[nt], af[mt], acc[mt][nt], 0,0,0);
  }

  // epilogue: per tile, lane holds m = lane&15 and n = quad*4 + {0..3} -> vector stores
  float4 b4[4];
  #pragma unroll
  for (int nt=0;nt<4;++nt)
    b4[nt] = *(const float4*)(bias + n0 + wn + nt*16 + quad*4);

  #pragma unroll
  for (int mt=0;mt<4;++mt){
    const int m = m0 + wm + mt*16 + row16;
    if (m >= M) continue;
    const float dg = (MODE==1) ? (float)(deg[m]+1) : 0.f;
    #pragma unroll
    for (int nt=0;nt<4;++nt){
      const int nb = n0 + wn + nt*16 + quad*4;
      if (MODE == 0){
        bf16x4 o = { (bf16_t)(acc[mt][nt][0] + b4[nt].x),
                     (bf16_t)(acc[mt][nt][1] + b4[nt].y),
                     (bf16_t)(acc[mt][nt][2] + b4[nt].z),
                     (bf16_t)(acc[mt][nt][3] + b4[nt].w) };
        *(bf16x4*)((bf16_t*)C + (size_t)m*N + nb) = o;
      } else {
        const float4 xr = *(const float4*)(xres + (size_t)m*N + nb);
        float4 o;
        o.x = fmaxf(acc[mt][nt][0] + dg*b4[nt].x, 0.f) + xr.x;
        o.y = fmaxf(acc[mt][nt][1] + dg*b4[nt].y, 0.f) + xr.y;
        o.z = fmaxf(acc[mt][nt][2] + dg*b4[nt].z, 0.f) + xr.z;
        o.w = fmaxf(acc[mt][nt][3] + dg*b4[nt].w, 0.f) + xr.w;
        *(float4*)((float*)C + (size_t)m*N + nb) = o;
      }
    }
  }
}

// ---------- fused attention: score + online softmax + aggregate, one wave per node ----------
// P layout: [0,256) q; [256,768) kv-packed: head h at 256+h*256, group g holds
// k[g*4..g*4+3] then v[g*4..g*4+3] -> ONE bf16x8 load per edge per lane.
// BATCHED x4: 4 independent kv loads + 4 independent shuffle-reduce chains per
// chunk, then ONE online-softmax update (max-of-4, single rescale). Converts
// the serial per-edge chain (load-latency x degree) into ~degree/4 exposures.
__device__ __forceinline__ float score4(bf16x8 kvv, float4 qv, float4 b1v, float4 w2v){
  return fmaxf(qv.x+(float)kvv[0]+b1v.x, 0.f)*w2v.x
       + fmaxf(qv.y+(float)kvv[1]+b1v.y, 0.f)*w2v.y
       + fmaxf(qv.z+(float)kvv[2]+b1v.z, 0.f)*w2v.z
       + fmaxf(qv.w+(float)kvv[3]+b1v.w, 0.f)*w2v.w;
}
__device__ __forceinline__ float hredux(float p){
  #pragma unroll
  for (int o = 16; o >= 1; o >>= 1)
    p += __shfl_xor(p, o, 64);
  return p;
}
__global__ __launch_bounds__(256) void fused_attn_kernel(
    const bf16_t* __restrict__ P, const int* __restrict__ bj, const int* __restrict__ off,
    const float* __restrict__ b1, const float* __restrict__ W2, const float* __restrict__ b2,
    bf16_t* __restrict__ aggb, int Nn)
{
  int i = blockIdx.x * (blockDim.x >> 6) + (threadIdx.x >> 6);
  if (i >= Nn) return;
  int lane = threadIdx.x & 63;
  int h = lane >> 5, g = lane & 31, d = g * 4;

  const float4 qv  = cvt4(*(const bf16x4*)(P + (size_t)i*768 + h*128 + d));
  const float4 b1v = *(const float4*)(b1 + d);
  const float4 w2v = *(const float4*)(W2 + d);
  const float b2v  = b2[0];
  const bf16_t* __restrict__ Pkv = P + 256 + h*256 + g*8;

  float m = -3.0e38f, s = 0.f;
  float4 acc = make_float4(0.f,0.f,0.f,0.f);
  const int s0 = off[i], s1 = off[i+1], s1m1 = s1 - 1;

  for (int t = s0; t < s1; t += 4){
    const int cnt = s1 - t;                 // >= 1
    // clamped indices: tail duplicates last edge (L1 hit, masked out below)
    const int jA = bj[t];
    const int jB = bj[min(t+1, s1m1)];
    const int jC = bj[min(t+2, s1m1)];
    const int jD = bj[min(t+3, s1m1)];
    // 4 independent row loads
    const bf16x8 kA = *(const bf16x8*)(Pkv + (size_t)jA*768);
    const bf16x8 kB = *(const bf16x8*)(Pkv + (size_t)jB*768);
    const bf16x8 kC = *(const bf16x8*)(Pkv + (size_t)jC*768);
    const bf16x8 kD = *(const bf16x8*)(Pkv + (size_t)jD*768);
    // 4 independent score chains
    float pA = hredux(score4(kA, qv, b1v, w2v));
    float pB = hredux(score4(kB, qv, b1v, w2v));
    float pC = hredux(score4(kC, qv, b1v, w2v));
    float pD = hredux(score4(kD, qv, b1v, w2v));
    const float aA = pA + b2v;
    const float aB = (cnt > 1) ? pB + b2v : -3.0e38f;
    const float aC = (cnt > 2) ? pC + b2v : -3.0e38f;
    const float aD = (cnt > 3) ? pD + b2v : -3.0e38f;
    // one online-softmax update per chunk
    const float amax = fmaxf(fmaxf(aA, aB), fmaxf(aC, aD));
    const float mn = fmaxf(m, amax);
    const float sc = __expf(m - mn);
    const float eA = __expf(aA - mn);       // masked lanes -> exp(-inf) = 0
    const float eB = __expf(aB - mn);
    const float eC = __expf(aC - mn);
    const float eD = __expf(aD - mn);
    s = s*sc + ((eA + eB) + (eC + eD));
    acc.x = acc.x*sc + ((eA*(float)kA[4] + eB*(float)kB[4]) + (eC*(float)kC[4] + eD*(float)kD[4]));
    acc.y = acc.y*sc + ((eA*(float)kA[5] + eB*(float)kB[5]) + (eC*(float)kC[5] + eD*(float)kD[5]));
    acc.z = acc.z*sc + ((eA*(float)kA[6] + eB*(float)kB[6]) + (eC*(float)kC[6] + eD*(float)kD[6]));
    acc.w = acc.w*sc + ((eA*(float)kA[7] + eB*(float)kB[7]) + (eC*(float)kC[7] + eD*(float)kD[7]));
    m = mn;
  }
  float inv = 1.f / (s + 1e-16f);
  bf16x4 ob = { (bf16_t)(acc.x*inv), (bf16_t)(acc.y*inv), (bf16_t)(acc.z*inv), (bf16_t)(acc.w*inv) };
  *(bf16x4*)(aggb + (size_t)i*256 + h*128 + d) = ob;
}

// ---------- launch ----------
extern "C" void kernel_launch(void* const* d_in, const int* in_sizes, int n_in,
                              void* d_out, int out_size, void* d_ws, size_t ws_size,
                              hipStream_t stream)
{
  const float* x     = (const float*)d_in[0];
  const int*   ei    = (const int*)d_in[1];
  const float* Wkqv  = (const float*)d_in[2];
  const float* bkqv  = (const float*)d_in[3];
  const float* W1    = (const float*)d_in[4];
  const float* b1    = (const float*)d_in[5];
  const float* W2    = (const float*)d_in[6];
  const float* b2    = (const float*)d_in[7];
  const float* Wout  = (const float*)d_in[8];
  const float* bout  = (const float*)d_in[9];
  float* out = (float*)d_out;

  const int N  = in_sizes[0] / EMB;   // 50000
  const int E0 = in_sizes[1] / 2;     // 100000
  const int E  = 2*E0 + N;            // 250000

  // workspace layout (fp32-word offsets; all 16B-aligned)
  float* base = (float*)d_ws;
  bf16_t* WcombT = (bf16_t*)base;                       // 768*256 bf16
  float*  bcomb  = base + 98304;                        // 768 w
  bf16_t* WoutT  = (bf16_t*)(base + 98304 + 768);       // 256*256 bf16
  bf16_t* xb     = (bf16_t*)(base + 131840);            // N*256 bf16
  bf16_t* Pb     = (bf16_t*)(base + 131840 + 6400000);  // N*768 bf16
  bf16_t* aggb   = (bf16_t*)(Pb + (size_t)N*768);       // N*256 bf16
  int* deg       = (int*)(aggb + (size_t)N*256);        // N
  int* cursor    = deg + N;                             // N
  int* flag      = cursor + N;                          // 1
  int* off       = flag + 1;                            // N+1
  int* bj        = off + (N+1);                         // E
  // scratch for scan block sums: reuse aggb region (written only later by attn)
  int* bsum      = (int*)aggb;                          // <=1024 ints

  hipMemsetAsync(deg, 0, (size_t)2*N*sizeof(int), stream);  // deg + cursor

  detect_kernel<<<1,1,0,stream>>>(ei, flag);
  cvt_x_kernel<<<((N*EMB/4)+255)/256,256,0,stream>>>(x, xb, N*EMB/4);
  prep_weights<<<dim3(3,257),256,0,stream>>>(Wkqv, bkqv, W1, WcombT, bcomb);
  prep_wout<<<256,256,0,stream>>>(Wout, WoutT);

  deg_kernel<<<(2*E0+255)/256,256,0,stream>>>(ei, flag, deg, E0, N);
  const int nb = (N + 1023)/1024;
  scan1_kernel<<<nb,1024,0,stream>>>(deg, off, bsum, N);
  scan2_kernel<<<1,1024,0,stream>>>(bsum, off, nb, N);
  scan3_kernel<<<(N+255)/256,256,0,stream>>>(off, bsum, N);
  scatter_kernel<<<(E+255)/256,256,0,stream>>>(ei, flag, off, cursor, bj, E0, N);

  const int nm8 = (((N+127)/128) + 7) & ~7;   // m-strips padded to multiple of 8
  mfma_gemm<0, bf16_t><<<nm8*6,256,0,stream>>>(xb, WcombT, bcomb, Pb, N, 768, nullptr, nullptr);
  fused_attn_kernel<<<(N+3)/4,256,0,stream>>>(Pb, bj, off, b1, W2, b2, aggb, N);
  mfma_gemm<1, float><<<nm8*2,256,0,stream>>>(aggb, WoutT, bout, out, N, 256, deg, x);
}

// Round 5
// 291.985 us; speedup vs baseline: 1.3013x; 1.0035x over previous
//
#include <hip/hip_runtime.h>
#include <hip/hip_bf16.h>

#define EMB 256

typedef __bf16 bf16_t;
typedef __attribute__((ext_vector_type(8))) __bf16 bf16x8;
typedef __attribute__((ext_vector_type(4))) __bf16 bf16x4;
typedef __attribute__((ext_vector_type(4))) float floatx4;

// ---------- helpers ----------
__device__ __forceinline__ int eidx(const int* __restrict__ p, int is64, long long k){
  return is64 ? p[2*k] : p[(int)k];
}
// async global->LDS, 16B per lane; LDS base must be WAVE-UNIFORM, lands at base + lane*16
__device__ __forceinline__ void async_load16(const void* g, void* l){
  __builtin_amdgcn_global_load_lds(
      (const __attribute__((address_space(1))) unsigned int*)g,
      (__attribute__((address_space(3))) unsigned int*)l,
      16, 0, 0);
}
__device__ __forceinline__ float4 cvt4(bf16x4 v){
  return make_float4((float)v.x, (float)v.y, (float)v.z, (float)v.w);
}
// inline dtype detect: int64 edge_index -> high words of first entries are 0
__device__ __forceinline__ int detect64(const int* __restrict__ ei){
  return ((ei[1] | ei[3] | ei[5] | ei[7]) == 0) ? 1 : 0;
}

// ---------- x -> bf16 ----------
__global__ void cvt_x_kernel(const float* __restrict__ x, bf16_t* __restrict__ xb, int n4){
  int t = blockIdx.x*blockDim.x + threadIdx.x;
  if (t >= n4) return;
  const float4 v = *(const float4*)(x + (size_t)t*4);
  bf16x4 o = { (bf16_t)v.x, (bf16_t)v.y, (bf16_t)v.z, (bf16_t)v.w };
  *(bf16x4*)(xb + (size_t)t*4) = o;
}

// ---------- fold W1 into Wkqv; emit TRANSPOSED bf16 WcombT[768][256] + fp32 bcomb[768] ----------
// Output column layout (KV-PACKED): cols [0,256) = q (h*128+d);
// cols [256,768): r = n-256, h = r>>8, g = (r&255)>>3, half = (r>>2)&1, dd = r&3, d = g*4+dd;
//   half 0 -> k_scaled[h][d], half 1 -> v[h][d].
__global__ void prep_weights(const float* __restrict__ Wkqv, const float* __restrict__ bkqv,
                             const float* __restrict__ W1,
                             bf16_t* __restrict__ WcombT, float* __restrict__ bcomb){
  int n = blockIdx.x * blockDim.x + threadIdx.x;   // 0..767 (output col, permuted layout)
  int c = blockIdx.y;                              // 0..256 (k index; 256 = bias)
  if (n >= 768) return;
  const float rs = rsqrtf(128.0f);
  bool isBias = (c == 256);
  const float* arow = isBias ? bkqv : (Wkqv + (size_t)c*768);
  float val;
  if (n < 256){                       // q
    int h = n >> 7, d = n & 127;
    float s = 0.f;
    for (int t = 0; t < 128; ++t)
      s = fmaf(arow[h*128 + t], W1[(size_t)(128 + t)*128 + d], s);
    val = s;
  } else {
    int r = n - 256;
    int h = r >> 8, t8 = r & 255;
    int g = t8 >> 3, half = (t8 >> 2) & 1, dd = t8 & 3;
    int d = g*4 + dd;
    if (half == 0){                   // k (scaled)
      float s = 0.f;
      for (int t = 0; t < 128; ++t)
        s = fmaf(arow[256 + h*128 + t], W1[(size_t)t*128 + d], s);
      val = s * rs;
    } else {                          // v passthrough
      val = arow[512 + h*128 + d];
    }
  }
  if (isBias) bcomb[n] = val;
  else        WcombT[(size_t)n*256 + c] = (bf16_t)val;
}

// ---------- Wout -> transposed bf16 WoutT[256][256] ----------
__global__ void prep_wout(const float* __restrict__ W, bf16_t* __restrict__ Wt){
  int t = blockIdx.x*blockDim.x + threadIdx.x;  // 65536
  int n = t & 255, c = t >> 8;
  Wt[(size_t)n*256 + c] = (bf16_t)W[(size_t)c*256 + n];
}

// ---------- degree count over the 2*E0 non-self edges (dst side) ----------
__global__ void deg_kernel(const int* __restrict__ ei,
                           int* __restrict__ deg, int E0, int Nn){
  int t = blockIdx.x*blockDim.x + threadIdx.x;
  if (t >= 2*E0) return;
  int is64 = detect64(ei);
  int i = (t < E0) ? eidx(ei,is64,(long long)E0+t) : eidx(ei,is64,t-E0);
  i = min(max(i,0), Nn-1);
  atomicAdd(deg + i, 1);
}

// ---------- hierarchical exclusive scan of (deg+1) -> off[0..N] ----------
// scan1: per-block (1024) local exclusive scan + block sums
__global__ __launch_bounds__(1024) void scan1_kernel(const int* __restrict__ deg,
                                                     int* __restrict__ off,
                                                     int* __restrict__ bsum, int N){
  __shared__ int wsum[16];
  int tid = threadIdx.x, lane = tid & 63, w = tid >> 6;
  int i = blockIdx.x*1024 + tid;
  int v = (i < N) ? (deg[i] + 1) : 0;
  int incl = v;
  #pragma unroll
  for (int o = 1; o < 64; o <<= 1){
    int t = __shfl_up(incl, o, 64);
    if (lane >= o) incl += t;
  }
  if (lane == 63) wsum[w] = incl;
  __syncthreads();
  if (w == 0 && lane < 16){
    int sv = wsum[lane];
    #pragma unroll
    for (int o = 1; o < 16; o <<= 1){
      int t = __shfl_up(sv, o, 64);
      if (lane >= o) sv += t;
    }
    wsum[lane] = sv;
  }
  __syncthreads();
  int wpref = (w == 0) ? 0 : wsum[w-1];
  if (i < N) off[i] = wpref + incl - v;          // block-local exclusive
  if (tid == 1023) bsum[blockIdx.x] = wpref + incl;  // block total
}

// scan2: single block scans bsum[nb] (nb<=1024) in place -> exclusive; writes grand total to off[N]
__global__ __launch_bounds__(1024) void scan2_kernel(int* __restrict__ bsum,
                                                     int* __restrict__ off, int nb, int N){
  __shared__ int wsum[16];
  int tid = threadIdx.x, lane = tid & 63, w = tid >> 6;
  int v = (tid < nb) ? bsum[tid] : 0;
  int incl = v;
  #pragma unroll
  for (int o = 1; o < 64; o <<= 1){
    int t = __shfl_up(incl, o, 64);
    if (lane >= o) incl += t;
  }
  if (lane == 63) wsum[w] = incl;
  __syncthreads();
  if (w == 0 && lane < 16){
    int sv = wsum[lane];
    #pragma unroll
    for (int o = 1; o < 16; o <<= 1){
      int t = __shfl_up(sv, o, 64);
      if (lane >= o) sv += t;
    }
    wsum[lane] = sv;
  }
  __syncthreads();
  int wpref = (w == 0) ? 0 : wsum[w-1];
  if (tid < nb) bsum[tid] = wpref + incl - v;    // exclusive block offsets
  if (tid == 1023) off[N] = wpref + incl;        // grand total
}

// scan3: add block offsets
__global__ void scan3_kernel(int* __restrict__ off, const int* __restrict__ bsum, int N){
  int i = blockIdx.x*256 + threadIdx.x;
  if (i < N) off[i] += bsum[i >> 10];
}

// ---------- scatter source index j into CSR buckets (incl. self-loops) ----------
__global__ void scatter_kernel(const int* __restrict__ ei,
                               const int* __restrict__ off, int* __restrict__ cursor,
                               int* __restrict__ bj, int E0, int Nn){
  int e = blockIdx.x*blockDim.x + threadIdx.x;
  int E = 2*E0 + Nn;
  if (e >= E) return;
  int is64 = detect64(ei);
  int j, i;
  if (e < E0){ j = eidx(ei,is64,e); i = eidx(ei,is64,(long long)E0+e); }
  else if (e < 2*E0){ int t = e - E0; i = eidx(ei,is64,t); j = eidx(ei,is64,(long long)E0+t); }
  else { i = j = e - 2*E0; }
  i = min(max(i,0), Nn-1); j = min(max(j,0), Nn-1);
  int pos = atomicAdd(cursor + i, 1);
  bj[off[i] + pos] = j;
}

// ---------- bf16 MFMA GEMM, K=256: C = A[M,256] @ Bt[N,256]^T + epilogue ----------
// 8-WAVE BLOCKS (512 thr), tile 128x128, wave owns 64x32 (acc 4x2 = 32 VGPR).
// Halved per-thread acc doubles waves/CU (16 vs 8.3) for latency hiding --
// the counter-diagnosed bottleneck (MfmaUtil/VALUBusy/HBM all idle at 4-wave).
// Double-buffered all-async LDS staging (8 waves x 2 loads = 16 frag-rows/kt).
// SWAPPED MFMA OPERANDS (D row=n_local, col=m_local) -> vectorized epilogue.
// MODE 0: C(bf16) = AB + bias[n]
// MODE 1: C(fp32) = relu(AB + (deg[m]+1)*bias[n]) + xres[m*N+n]
template<int MODE, typename OutT>
__global__ __launch_bounds__(512, 4) void mfma_gemm(
    const bf16_t* __restrict__ A, const bf16_t* __restrict__ Bt,
    const float* __restrict__ bias, OutT* __restrict__ C,
    int M, int N,
    const int* __restrict__ deg, const float* __restrict__ xres)
{
  __shared__ bf16_t As[2][128*32];   // 8 KB each
  __shared__ bf16_t Bs[2][128*32];
  const int tid = threadIdx.x;
  const int wave = tid >> 6, lane = tid & 63;   // wave 0..7
  const int row16 = lane & 15, quad = lane >> 4;

  // XCD swizzle: bid%8 = XCD (dispatch round-robin heuristic); n fastest per XCD
  const int nn = N >> 7;
  const int bid = blockIdx.x;
  const int strip = bid / (8*nn);
  const int inner = bid % (8*nn);
  const int m0 = (strip*8 + (inner & 7)) * 128;
  const int n0 = (inner >> 3) * 128;
  const int wm  = (wave >> 2) * 64;   // 0 or 64
  const int wnq = (wave & 3) * 32;    // 0,32,64,96

  const int f0 = wave;                // staging frag-row 0..7
  const int gm0 = min(m0 + f0*16 + row16, M-1);
  const int gn0 = n0 + f0*16 + row16;

  // prologue: stage k-tile 0 into buffer 0
  async_load16(A  + (size_t)gm0*256 + quad*8, (char*)As[0] + f0*1024);
  async_load16(Bt + (size_t)gn0*256 + quad*8, (char*)Bs[0] + f0*1024);

  floatx4 acc[4][2];
  #pragma unroll
  for (int a=0;a<4;++a)
    #pragma unroll
    for (int b=0;b<2;++b) acc[a][b] = (floatx4){0.f,0.f,0.f,0.f};

  #pragma unroll
  for (int kt = 0; kt < 8; ++kt){
    const int cur = kt & 1, nxt = cur ^ 1;
    const int k1 = (kt+1)*32;

    __syncthreads();   // buffer[cur] staged; buffer[nxt] free

    if (kt < 7){
      async_load16(A  + (size_t)gm0*256 + k1 + quad*8, (char*)As[nxt] + f0*1024);
      async_load16(Bt + (size_t)gn0*256 + k1 + quad*8, (char*)Bs[nxt] + f0*1024);
    }

    bf16x8 af[4], bfr[2];
    #pragma unroll
    for (int t = 0; t < 4; ++t)
      af[t]  = *(const bf16x8*)((const char*)As[cur] + ((wm>>4)+t)*1024 + lane*16);
    #pragma unroll
    for (int u = 0; u < 2; ++u)
      bfr[u] = *(const bf16x8*)((const char*)Bs[cur] + ((wnq>>4)+u)*1024 + lane*16);

    // SWAPPED operands: D tile gets row=n_local, col=m_local
    #pragma unroll
    for (int mt=0;mt<4;++mt)
      #pragma unroll
      for (int nt=0;nt<2;++nt)
        acc[mt][nt] = __builtin_amdgcn_mfma_f32_16x16x32_bf16(bfr[nt], af[mt], acc[mt][nt], 0,0,0);
  }

  // epilogue: per tile, lane holds m = lane&15 and n = quad*4 + {0..3} -> vector stores
  float4 b4[2];
  #pragma unroll
  for (int nt=0;nt<2;++nt)
    b4[nt] = *(const float4*)(bias + n0 + wnq + nt*16 + quad*4);

  #pragma unroll
  for (int mt=0;mt<4;++mt){
    const int m = m0 + wm + mt*16 + row16;
    if (m >= M) continue;
    const float dg = (MODE==1) ? (float)(deg[m]+1) : 0.f;
    #pragma unroll
    for (int nt=0;nt<2;++nt){
      const int nb = n0 + wnq + nt*16 + quad*4;
      if (MODE == 0){
        bf16x4 o = { (bf16_t)(acc[mt][nt][0] + b4[nt].x),
                     (bf16_t)(acc[mt][nt][1] + b4[nt].y),
                     (bf16_t)(acc[mt][nt][2] + b4[nt].z),
                     (bf16_t)(acc[mt][nt][3] + b4[nt].w) };
        *(bf16x4*)((bf16_t*)C + (size_t)m*N + nb) = o;
      } else {
        const float4 xr = *(const float4*)(xres + (size_t)m*N + nb);
        float4 o;
        o.x = fmaxf(acc[mt][nt][0] + dg*b4[nt].x, 0.f) + xr.x;
        o.y = fmaxf(acc[mt][nt][1] + dg*b4[nt].y, 0.f) + xr.y;
        o.z = fmaxf(acc[mt][nt][2] + dg*b4[nt].z, 0.f) + xr.z;
        o.w = fmaxf(acc[mt][nt][3] + dg*b4[nt].w, 0.f) + xr.w;
        *(float4*)((float*)C + (size_t)m*N + nb) = o;
      }
    }
  }
}

// ---------- fused attention: score + online softmax + aggregate, one wave per node ----------
// P layout: [0,256) q; [256,768) kv-packed: head h at 256+h*256, group g holds
// k[g*4..g*4+3] then v[g*4..g*4+3] -> ONE bf16x8 load per edge per lane.
// BATCHED x4: 4 independent kv loads + 4 independent shuffle-reduce chains per
// chunk, then ONE online-softmax update (max-of-4, single rescale).
__device__ __forceinline__ float score4(bf16x8 kvv, float4 qv, float4 b1v, float4 w2v){
  return fmaxf(qv.x+(float)kvv[0]+b1v.x, 0.f)*w2v.x
       + fmaxf(qv.y+(float)kvv[1]+b1v.y, 0.f)*w2v.y
       + fmaxf(qv.z+(float)kvv[2]+b1v.z, 0.f)*w2v.z
       + fmaxf(qv.w+(float)kvv[3]+b1v.w, 0.f)*w2v.w;
}
__device__ __forceinline__ float hredux(float p){
  #pragma unroll
  for (int o = 16; o >= 1; o >>= 1)
    p += __shfl_xor(p, o, 64);
  return p;
}
__global__ __launch_bounds__(256) void fused_attn_kernel(
    const bf16_t* __restrict__ P, const int* __restrict__ bj, const int* __restrict__ off,
    const float* __restrict__ b1, const float* __restrict__ W2, const float* __restrict__ b2,
    bf16_t* __restrict__ aggb, int Nn)
{
  int i = blockIdx.x * (blockDim.x >> 6) + (threadIdx.x >> 6);
  if (i >= Nn) return;
  int lane = threadIdx.x & 63;
  int h = lane >> 5, g = lane & 31, d = g * 4;

  const float4 qv  = cvt4(*(const bf16x4*)(P + (size_t)i*768 + h*128 + d));
  const float4 b1v = *(const float4*)(b1 + d);
  const float4 w2v = *(const float4*)(W2 + d);
  const float b2v  = b2[0];
  const bf16_t* __restrict__ Pkv = P + 256 + h*256 + g*8;

  float m = -3.0e38f, s = 0.f;
  float4 acc = make_float4(0.f,0.f,0.f,0.f);
  const int s0 = off[i], s1 = off[i+1], s1m1 = s1 - 1;

  for (int t = s0; t < s1; t += 4){
    const int cnt = s1 - t;                 // >= 1
    const int jA = bj[t];
    const int jB = bj[min(t+1, s1m1)];
    const int jC = bj[min(t+2, s1m1)];
    const int jD = bj[min(t+3, s1m1)];
    const bf16x8 kA = *(const bf16x8*)(Pkv + (size_t)jA*768);
    const bf16x8 kB = *(const bf16x8*)(Pkv + (size_t)jB*768);
    const bf16x8 kC = *(const bf16x8*)(Pkv + (size_t)jC*768);
    const bf16x8 kD = *(const bf16x8*)(Pkv + (size_t)jD*768);
    float pA = hredux(score4(kA, qv, b1v, w2v));
    float pB = hredux(score4(kB, qv, b1v, w2v));
    float pC = hredux(score4(kC, qv, b1v, w2v));
    float pD = hredux(score4(kD, qv, b1v, w2v));
    const float aA = pA + b2v;
    const float aB = (cnt > 1) ? pB + b2v : -3.0e38f;
    const float aC = (cnt > 2) ? pC + b2v : -3.0e38f;
    const float aD = (cnt > 3) ? pD + b2v : -3.0e38f;
    const float amax = fmaxf(fmaxf(aA, aB), fmaxf(aC, aD));
    const float mn = fmaxf(m, amax);
    const float sc = __expf(m - mn);
    const float eA = __expf(aA - mn);       // masked lanes -> exp(-inf) = 0
    const float eB = __expf(aB - mn);
    const float eC = __expf(aC - mn);
    const float eD = __expf(aD - mn);
    s = s*sc + ((eA + eB) + (eC + eD));
    acc.x = acc.x*sc + ((eA*(float)kA[4] + eB*(float)kB[4]) + (eC*(float)kC[4] + eD*(float)kD[4]));
    acc.y = acc.y*sc + ((eA*(float)kA[5] + eB*(float)kB[5]) + (eC*(float)kC[5] + eD*(float)kD[5]));
    acc.z = acc.z*sc + ((eA*(float)kA[6] + eB*(float)kB[6]) + (eC*(float)kC[6] + eD*(float)kD[6]));
    acc.w = acc.w*sc + ((eA*(float)kA[7] + eB*(float)kB[7]) + (eC*(float)kC[7] + eD*(float)kD[7]));
    m = mn;
  }
  float inv = 1.f / (s + 1e-16f);
  bf16x4 ob = { (bf16_t)(acc.x*inv), (bf16_t)(acc.y*inv), (bf16_t)(acc.z*inv), (bf16_t)(acc.w*inv) };
  *(bf16x4*)(aggb + (size_t)i*256 + h*128 + d) = ob;
}

// ---------- launch ----------
extern "C" void kernel_launch(void* const* d_in, const int* in_sizes, int n_in,
                              void* d_out, int out_size, void* d_ws, size_t ws_size,
                              hipStream_t stream)
{
  const float* x     = (const float*)d_in[0];
  const int*   ei    = (const int*)d_in[1];
  const float* Wkqv  = (const float*)d_in[2];
  const float* bkqv  = (const float*)d_in[3];
  const float* W1    = (const float*)d_in[4];
  const float* b1    = (const float*)d_in[5];
  const float* W2    = (const float*)d_in[6];
  const float* b2    = (const float*)d_in[7];
  const float* Wout  = (const float*)d_in[8];
  const float* bout  = (const float*)d_in[9];
  float* out = (float*)d_out;

  const int N  = in_sizes[0] / EMB;   // 50000
  const int E0 = in_sizes[1] / 2;     // 100000
  const int E  = 2*E0 + N;            // 250000

  // workspace layout (fp32-word offsets; all 16B-aligned)
  float* base = (float*)d_ws;
  bf16_t* WcombT = (bf16_t*)base;                       // 768*256 bf16
  float*  bcomb  = base + 98304;                        // 768 w
  bf16_t* WoutT  = (bf16_t*)(base + 98304 + 768);       // 256*256 bf16
  bf16_t* xb     = (bf16_t*)(base + 131840);            // N*256 bf16
  bf16_t* Pb     = (bf16_t*)(base + 131840 + 6400000);  // N*768 bf16
  bf16_t* aggb   = (bf16_t*)(Pb + (size_t)N*768);       // N*256 bf16
  int* deg       = (int*)(aggb + (size_t)N*256);        // N
  int* cursor    = deg + N;                             // N
  int* flag      = cursor + N;                          // 1 (unused)
  int* off       = flag + 1;                            // N+1
  int* bj        = off + (N+1);                         // E
  // scratch for scan block sums: reuse aggb region (written only later by attn)
  int* bsum      = (int*)aggb;                          // <=1024 ints

  hipMemsetAsync(deg, 0, (size_t)2*N*sizeof(int), stream);  // deg + cursor

  cvt_x_kernel<<<((N*EMB/4)+255)/256,256,0,stream>>>(x, xb, N*EMB/4);
  prep_weights<<<dim3(3,257),256,0,stream>>>(Wkqv, bkqv, W1, WcombT, bcomb);
  prep_wout<<<256,256,0,stream>>>(Wout, WoutT);

  deg_kernel<<<(2*E0+255)/256,256,0,stream>>>(ei, deg, E0, N);
  const int nb = (N + 1023)/1024;
  scan1_kernel<<<nb,1024,0,stream>>>(deg, off, bsum, N);
  scan2_kernel<<<1,1024,0,stream>>>(bsum, off, nb, N);
  scan3_kernel<<<(N+255)/256,256,0,stream>>>(off, bsum, N);
  scatter_kernel<<<(E+255)/256,256,0,stream>>>(ei, off, cursor, bj, E0, N);

  const int nm8 = (((N+127)/128) + 7) & ~7;   // m-strips padded to multiple of 8
  mfma_gemm<0, bf16_t><<<nm8*6,512,0,stream>>>(xb, WcombT, bcomb, Pb, N, 768, nullptr, nullptr);
  fused_attn_kernel<<<(N+3)/4,256,0,stream>>>(Pb, bj, off, b1, W2, b2, aggb, N);
  mfma_gemm<1, float><<<nm8*2,512,0,stream>>>(aggb, WoutT, bout, out, N, 256, deg, x);
}

// Round 6
// 290.075 us; speedup vs baseline: 1.3099x; 1.0066x over previous
//
#include <hip/hip_runtime.h>
#include <hip/hip_bf16.h>

#define EMB 256

typedef __bf16 bf16_t;
typedef __attribute__((ext_vector_type(8))) __bf16 bf16x8;
typedef __attribute__((ext_vector_type(4))) __bf16 bf16x4;
typedef __attribute__((ext_vector_type(4))) float floatx4;

// ---------- helpers ----------
__device__ __forceinline__ int eidx(const int* __restrict__ p, int is64, long long k){
  return is64 ? p[2*k] : p[(int)k];
}
// async global->LDS, 16B per lane; LDS base must be WAVE-UNIFORM, lands at base + lane*16
__device__ __forceinline__ void async_load16(const void* g, void* l){
  __builtin_amdgcn_global_load_lds(
      (const __attribute__((address_space(1))) unsigned int*)g,
      (__attribute__((address_space(3))) unsigned int*)l,
      16, 0, 0);
}
__device__ __forceinline__ float4 cvt4(bf16x4 v){
  return make_float4((float)v.x, (float)v.y, (float)v.z, (float)v.w);
}
// inline dtype detect: int64 edge_index -> high words of first entries are 0
__device__ __forceinline__ int detect64(const int* __restrict__ ei){
  return ((ei[1] | ei[3] | ei[5] | ei[7]) == 0) ? 1 : 0;
}

// ---------- x -> bf16 ----------
__global__ void cvt_x_kernel(const float* __restrict__ x, bf16_t* __restrict__ xb, int n4){
  int t = blockIdx.x*blockDim.x + threadIdx.x;
  if (t >= n4) return;
  const float4 v = *(const float4*)(x + (size_t)t*4);
  bf16x4 o = { (bf16_t)v.x, (bf16_t)v.y, (bf16_t)v.z, (bf16_t)v.w };
  *(bf16x4*)(xb + (size_t)t*4) = o;
}

// ---------- fold W1 into Wkqv; emit TRANSPOSED bf16 WcombT[768][256] + fp32 bcomb[768] ----------
// Output column layout (KV-PACKED): cols [0,256) = q (h*128+d);
// cols [256,768): r = n-256, h = r>>8, g = (r&255)>>3, half = (r>>2)&1, dd = r&3, d = g*4+dd;
//   half 0 -> k_scaled[h][d], half 1 -> v[h][d].
__global__ void prep_weights(const float* __restrict__ Wkqv, const float* __restrict__ bkqv,
                             const float* __restrict__ W1,
                             bf16_t* __restrict__ WcombT, float* __restrict__ bcomb){
  int n = blockIdx.x * blockDim.x + threadIdx.x;   // 0..767 (output col, permuted layout)
  int c = blockIdx.y;                              // 0..256 (k index; 256 = bias)
  if (n >= 768) return;
  const float rs = rsqrtf(128.0f);
  bool isBias = (c == 256);
  const float* arow = isBias ? bkqv : (Wkqv + (size_t)c*768);
  float val;
  if (n < 256){                       // q
    int h = n >> 7, d = n & 127;
    float s = 0.f;
    for (int t = 0; t < 128; ++t)
      s = fmaf(arow[h*128 + t], W1[(size_t)(128 + t)*128 + d], s);
    val = s;
  } else {
    int r = n - 256;
    int h = r >> 8, t8 = r & 255;
    int g = t8 >> 3, half = (t8 >> 2) & 1, dd = t8 & 3;
    int d = g*4 + dd;
    if (half == 0){                   // k (scaled)
      float s = 0.f;
      for (int t = 0; t < 128; ++t)
        s = fmaf(arow[256 + h*128 + t], W1[(size_t)t*128 + d], s);
      val = s * rs;
    } else {                          // v passthrough
      val = arow[512 + h*128 + d];
    }
  }
  if (isBias) bcomb[n] = val;
  else        WcombT[(size_t)n*256 + c] = (bf16_t)val;
}

// ---------- Wout -> transposed bf16 WoutT[256][256] ----------
__global__ void prep_wout(const float* __restrict__ W, bf16_t* __restrict__ Wt){
  int t = blockIdx.x*blockDim.x + threadIdx.x;  // 65536
  int n = t & 255, c = t >> 8;
  Wt[(size_t)n*256 + c] = (bf16_t)W[(size_t)c*256 + n];
}

// ---------- degree count over the 2*E0 non-self edges (dst side) ----------
__global__ void deg_kernel(const int* __restrict__ ei,
                           int* __restrict__ deg, int E0, int Nn){
  int t = blockIdx.x*blockDim.x + threadIdx.x;
  if (t >= 2*E0) return;
  int is64 = detect64(ei);
  int i = (t < E0) ? eidx(ei,is64,(long long)E0+t) : eidx(ei,is64,t-E0);
  i = min(max(i,0), Nn-1);
  atomicAdd(deg + i, 1);
}

// ---------- hierarchical exclusive scan of (deg+1) -> off[0..N] ----------
__global__ __launch_bounds__(1024) void scan1_kernel(const int* __restrict__ deg,
                                                     int* __restrict__ off,
                                                     int* __restrict__ bsum, int N){
  __shared__ int wsum[16];
  int tid = threadIdx.x, lane = tid & 63, w = tid >> 6;
  int i = blockIdx.x*1024 + tid;
  int v = (i < N) ? (deg[i] + 1) : 0;
  int incl = v;
  #pragma unroll
  for (int o = 1; o < 64; o <<= 1){
    int t = __shfl_up(incl, o, 64);
    if (lane >= o) incl += t;
  }
  if (lane == 63) wsum[w] = incl;
  __syncthreads();
  if (w == 0 && lane < 16){
    int sv = wsum[lane];
    #pragma unroll
    for (int o = 1; o < 16; o <<= 1){
      int t = __shfl_up(sv, o, 64);
      if (lane >= o) sv += t;
    }
    wsum[lane] = sv;
  }
  __syncthreads();
  int wpref = (w == 0) ? 0 : wsum[w-1];
  if (i < N) off[i] = wpref + incl - v;          // block-local exclusive
  if (tid == 1023) bsum[blockIdx.x] = wpref + incl;  // block total
}

__global__ __launch_bounds__(1024) void scan2_kernel(int* __restrict__ bsum,
                                                     int* __restrict__ off, int nb, int N){
  __shared__ int wsum[16];
  int tid = threadIdx.x, lane = tid & 63, w = tid >> 6;
  int v = (tid < nb) ? bsum[tid] : 0;
  int incl = v;
  #pragma unroll
  for (int o = 1; o < 64; o <<= 1){
    int t = __shfl_up(incl, o, 64);
    if (lane >= o) incl += t;
  }
  if (lane == 63) wsum[w] = incl;
  __syncthreads();
  if (w == 0 && lane < 16){
    int sv = wsum[lane];
    #pragma unroll
    for (int o = 1; o < 16; o <<= 1){
      int t = __shfl_up(sv, o, 64);
      if (lane >= o) sv += t;
    }
    wsum[lane] = sv;
  }
  __syncthreads();
  int wpref = (w == 0) ? 0 : wsum[w-1];
  if (tid < nb) bsum[tid] = wpref + incl - v;    // exclusive block offsets
  if (tid == 1023) off[N] = wpref + incl;        // grand total
}

__global__ void scan3_kernel(int* __restrict__ off, const int* __restrict__ bsum, int N){
  int i = blockIdx.x*256 + threadIdx.x;
  if (i < N) off[i] += bsum[i >> 10];
}

// ---------- scatter source index j into CSR buckets (incl. self-loops) ----------
__global__ void scatter_kernel(const int* __restrict__ ei,
                               const int* __restrict__ off, int* __restrict__ cursor,
                               int* __restrict__ bj, int E0, int Nn){
  int e = blockIdx.x*blockDim.x + threadIdx.x;
  int E = 2*E0 + Nn;
  if (e >= E) return;
  int is64 = detect64(ei);
  int j, i;
  if (e < E0){ j = eidx(ei,is64,e); i = eidx(ei,is64,(long long)E0+e); }
  else if (e < 2*E0){ int t = e - E0; i = eidx(ei,is64,t); j = eidx(ei,is64,(long long)E0+t); }
  else { i = j = e - 2*E0; }
  i = min(max(i,0), Nn-1); j = min(max(j,0), Nn-1);
  int pos = atomicAdd(cursor + i, 1);
  bj[off[i] + pos] = j;
}

// ---------- 256x256-tile bf16 MFMA GEMM (MODE 0), K=256 ----------
// THEORY: the 128^2 kernel is L3-fabric-byte-bound: tile re-fetch = 
// M*N*K*2*(1/BM+1/BN) = 301 MB at ~6.5 TB/s L3 service ~= the observed 61 us,
// invariant to all scheduling changes. BM=BN=256 halves re-fetch to 154 MB.
// 1024 thr (16 waves), wave owns 64x64 (acc 4x4 = 64 VGPR), LDS 64 KB dbuf,
// same proven 2-barrier skeleton; per wave per k-step: 1 A + 1 B frag-row
// staged via global_load_lds. Numerics identical to 128^2 version.
__global__ __launch_bounds__(1024, 4) void mfma_gemm256(
    const bf16_t* __restrict__ A, const bf16_t* __restrict__ Bt,
    const float* __restrict__ bias, bf16_t* __restrict__ C,
    int M, int N)
{
  __shared__ bf16_t As[2][256*32];   // 16 KB each
  __shared__ bf16_t Bs[2][256*32];
  const int tid = threadIdx.x;
  const int wave = tid >> 6, lane = tid & 63;   // wave 0..15
  const int row16 = lane & 15, quad = lane >> 4;

  // XCD swizzle: consecutive bids round-robin XCDs; n-tiles of an m-strip-octet together
  const int nn = N >> 8;               // n-strips of 256
  const int bid = blockIdx.x;
  const int strip = bid / (8*nn);
  const int inner = bid % (8*nn);
  const int m0 = (strip*8 + (inner & 7)) * 256;
  const int n0 = (inner >> 3) * 256;
  const int wm  = (wave >> 2) * 64;    // 0,64,128,192
  const int wnq = (wave & 3) * 64;     // 0,64,128,192

  // staging: wave w owns A frag-row w and B frag-row w (16 rows x 32 k each)
  const int gm0 = min(m0 + wave*16 + row16, M-1);
  const int gn0 = n0 + wave*16 + row16;

  // prologue: stage k-tile 0 into buffer 0
  async_load16(A  + (size_t)gm0*256 + quad*8, (char*)As[0] + wave*1024);
  async_load16(Bt + (size_t)gn0*256 + quad*8, (char*)Bs[0] + wave*1024);

  floatx4 acc[4][4];
  #pragma unroll
  for (int a=0;a<4;++a)
    #pragma unroll
    for (int b=0;b<4;++b) acc[a][b] = (floatx4){0.f,0.f,0.f,0.f};

  #pragma unroll
  for (int kt = 0; kt < 8; ++kt){
    const int cur = kt & 1, nxt = cur ^ 1;
    const int k1 = (kt+1)*32;

    __syncthreads();   // buffer[cur] staged; buffer[nxt] free

    if (kt < 7){
      async_load16(A  + (size_t)gm0*256 + k1 + quad*8, (char*)As[nxt] + wave*1024);
      async_load16(Bt + (size_t)gn0*256 + k1 + quad*8, (char*)Bs[nxt] + wave*1024);
    }

    bf16x8 af[4], bfr[4];
    #pragma unroll
    for (int t = 0; t < 4; ++t){
      af[t]  = *(const bf16x8*)((const char*)As[cur] + ((wm>>4)+t)*1024 + lane*16);
      bfr[t] = *(const bf16x8*)((const char*)Bs[cur] + ((wnq>>4)+t)*1024 + lane*16);
    }
    // SWAPPED operands: D tile gets row=n_local, col=m_local
    #pragma unroll
    for (int mt=0;mt<4;++mt)
      #pragma unroll
      for (int nt=0;nt<4;++nt)
        acc[mt][nt] = __builtin_amdgcn_mfma_f32_16x16x32_bf16(bfr[nt], af[mt], acc[mt][nt], 0,0,0);
  }

  // epilogue: lane holds m = lane&15, n = quad*4 + {0..3} per tile -> 8B stores
  float4 b4[4];
  #pragma unroll
  for (int nt=0;nt<4;++nt)
    b4[nt] = *(const float4*)(bias + n0 + wnq + nt*16 + quad*4);

  #pragma unroll
  for (int mt=0;mt<4;++mt){
    const int m = m0 + wm + mt*16 + row16;
    if (m >= M) continue;
    #pragma unroll
    for (int nt=0;nt<4;++nt){
      const int nb = n0 + wnq + nt*16 + quad*4;
      bf16x4 o = { (bf16_t)(acc[mt][nt][0] + b4[nt].x),
                   (bf16_t)(acc[mt][nt][1] + b4[nt].y),
                   (bf16_t)(acc[mt][nt][2] + b4[nt].z),
                   (bf16_t)(acc[mt][nt][3] + b4[nt].w) };
      *(bf16x4*)(C + (size_t)m*N + nb) = o;
    }
  }
}

// ---------- 128x128-tile bf16 MFMA GEMM (MODE 1 epilogue), 512 thr ----------
// out = relu(AB + (deg[m]+1)*bias[n]) + xres[m*N+n], fp32 out. Traffic here is
// xres/out-dominated so the 128^2 tile is kept (byte cut would be marginal).
__global__ __launch_bounds__(512, 4) void mfma_gemm_m1(
    const bf16_t* __restrict__ A, const bf16_t* __restrict__ Bt,
    const float* __restrict__ bias, float* __restrict__ C,
    int M, int N,
    const int* __restrict__ deg, const float* __restrict__ xres)
{
  __shared__ bf16_t As[2][128*32];   // 8 KB each
  __shared__ bf16_t Bs[2][128*32];
  const int tid = threadIdx.x;
  const int wave = tid >> 6, lane = tid & 63;   // wave 0..7
  const int row16 = lane & 15, quad = lane >> 4;

  const int nn = N >> 7;
  const int bid = blockIdx.x;
  const int strip = bid / (8*nn);
  const int inner = bid % (8*nn);
  const int m0 = (strip*8 + (inner & 7)) * 128;
  const int n0 = (inner >> 3) * 128;
  const int wm  = (wave >> 2) * 64;   // 0 or 64
  const int wnq = (wave & 3) * 32;    // 0,32,64,96

  const int f0 = wave;                // staging frag-row 0..7
  const int gm0 = min(m0 + f0*16 + row16, M-1);
  const int gn0 = n0 + f0*16 + row16;

  async_load16(A  + (size_t)gm0*256 + quad*8, (char*)As[0] + f0*1024);
  async_load16(Bt + (size_t)gn0*256 + quad*8, (char*)Bs[0] + f0*1024);

  floatx4 acc[4][2];
  #pragma unroll
  for (int a=0;a<4;++a)
    #pragma unroll
    for (int b=0;b<2;++b) acc[a][b] = (floatx4){0.f,0.f,0.f,0.f};

  #pragma unroll
  for (int kt = 0; kt < 8; ++kt){
    const int cur = kt & 1, nxt = cur ^ 1;
    const int k1 = (kt+1)*32;

    __syncthreads();

    if (kt < 7){
      async_load16(A  + (size_t)gm0*256 + k1 + quad*8, (char*)As[nxt] + f0*1024);
      async_load16(Bt + (size_t)gn0*256 + k1 + quad*8, (char*)Bs[nxt] + f0*1024);
    }

    bf16x8 af[4], bfr[2];
    #pragma unroll
    for (int t = 0; t < 4; ++t)
      af[t]  = *(const bf16x8*)((const char*)As[cur] + ((wm>>4)+t)*1024 + lane*16);
    #pragma unroll
    for (int u = 0; u < 2; ++u)
      bfr[u] = *(const bf16x8*)((const char*)Bs[cur] + ((wnq>>4)+u)*1024 + lane*16);

    #pragma unroll
    for (int mt=0;mt<4;++mt)
      #pragma unroll
      for (int nt=0;nt<2;++nt)
        acc[mt][nt] = __builtin_amdgcn_mfma_f32_16x16x32_bf16(bfr[nt], af[mt], acc[mt][nt], 0,0,0);
  }

  float4 b4[2];
  #pragma unroll
  for (int nt=0;nt<2;++nt)
    b4[nt] = *(const float4*)(bias + n0 + wnq + nt*16 + quad*4);

  #pragma unroll
  for (int mt=0;mt<4;++mt){
    const int m = m0 + wm + mt*16 + row16;
    if (m >= M) continue;
    const float dg = (float)(deg[m]+1);
    #pragma unroll
    for (int nt=0;nt<2;++nt){
      const int nb = n0 + wnq + nt*16 + quad*4;
      const float4 xr = *(const float4*)(xres + (size_t)m*N + nb);
      float4 o;
      o.x = fmaxf(acc[mt][nt][0] + dg*b4[nt].x, 0.f) + xr.x;
      o.y = fmaxf(acc[mt][nt][1] + dg*b4[nt].y, 0.f) + xr.y;
      o.z = fmaxf(acc[mt][nt][2] + dg*b4[nt].z, 0.f) + xr.z;
      o.w = fmaxf(acc[mt][nt][3] + dg*b4[nt].w, 0.f) + xr.w;
      *(float4*)(C + (size_t)m*N + nb) = o;
    }
  }
}

// ---------- fused attention: score + online softmax + aggregate, one wave per node ----------
// P layout: [0,256) q; [256,768) kv-packed. BATCHED x4 (see round-4 notes).
__device__ __forceinline__ float score4(bf16x8 kvv, float4 qv, float4 b1v, float4 w2v){
  return fmaxf(qv.x+(float)kvv[0]+b1v.x, 0.f)*w2v.x
       + fmaxf(qv.y+(float)kvv[1]+b1v.y, 0.f)*w2v.y
       + fmaxf(qv.z+(float)kvv[2]+b1v.z, 0.f)*w2v.z
       + fmaxf(qv.w+(float)kvv[3]+b1v.w, 0.f)*w2v.w;
}
__device__ __forceinline__ float hredux(float p){
  #pragma unroll
  for (int o = 16; o >= 1; o >>= 1)
    p += __shfl_xor(p, o, 64);
  return p;
}
__global__ __launch_bounds__(256) void fused_attn_kernel(
    const bf16_t* __restrict__ P, const int* __restrict__ bj, const int* __restrict__ off,
    const float* __restrict__ b1, const float* __restrict__ W2, const float* __restrict__ b2,
    bf16_t* __restrict__ aggb, int Nn)
{
  int i = blockIdx.x * (blockDim.x >> 6) + (threadIdx.x >> 6);
  if (i >= Nn) return;
  int lane = threadIdx.x & 63;
  int h = lane >> 5, g = lane & 31, d = g * 4;

  const float4 qv  = cvt4(*(const bf16x4*)(P + (size_t)i*768 + h*128 + d));
  const float4 b1v = *(const float4*)(b1 + d);
  const float4 w2v = *(const float4*)(W2 + d);
  const float b2v  = b2[0];
  const bf16_t* __restrict__ Pkv = P + 256 + h*256 + g*8;

  float m = -3.0e38f, s = 0.f;
  float4 acc = make_float4(0.f,0.f,0.f,0.f);
  const int s0 = off[i], s1 = off[i+1], s1m1 = s1 - 1;

  for (int t = s0; t < s1; t += 4){
    const int cnt = s1 - t;                 // >= 1
    const int jA = bj[t];
    const int jB = bj[min(t+1, s1m1)];
    const int jC = bj[min(t+2, s1m1)];
    const int jD = bj[min(t+3, s1m1)];
    const bf16x8 kA = *(const bf16x8*)(Pkv + (size_t)jA*768);
    const bf16x8 kB = *(const bf16x8*)(Pkv + (size_t)jB*768);
    const bf16x8 kC = *(const bf16x8*)(Pkv + (size_t)jC*768);
    const bf16x8 kD = *(const bf16x8*)(Pkv + (size_t)jD*768);
    float pA = hredux(score4(kA, qv, b1v, w2v));
    float pB = hredux(score4(kB, qv, b1v, w2v));
    float pC = hredux(score4(kC, qv, b1v, w2v));
    float pD = hredux(score4(kD, qv, b1v, w2v));
    const float aA = pA + b2v;
    const float aB = (cnt > 1) ? pB + b2v : -3.0e38f;
    const float aC = (cnt > 2) ? pC + b2v : -3.0e38f;
    const float aD = (cnt > 3) ? pD + b2v : -3.0e38f;
    const float amax = fmaxf(fmaxf(aA, aB), fmaxf(aC, aD));
    const float mn = fmaxf(m, amax);
    const float sc = __expf(m - mn);
    const float eA = __expf(aA - mn);       // masked lanes -> exp(-inf) = 0
    const float eB = __expf(aB - mn);
    const float eC = __expf(aC - mn);
    const float eD = __expf(aD - mn);
    s = s*sc + ((eA + eB) + (eC + eD));
    acc.x = acc.x*sc + ((eA*(float)kA[4] + eB*(float)kB[4]) + (eC*(float)kC[4] + eD*(float)kD[4]));
    acc.y = acc.y*sc + ((eA*(float)kA[5] + eB*(float)kB[5]) + (eC*(float)kC[5] + eD*(float)kD[5]));
    acc.z = acc.z*sc + ((eA*(float)kA[6] + eB*(float)kB[6]) + (eC*(float)kC[6] + eD*(float)kD[6]));
    acc.w = acc.w*sc + ((eA*(float)kA[7] + eB*(float)kB[7]) + (eC*(float)kC[7] + eD*(float)kD[7]));
    m = mn;
  }
  float inv = 1.f / (s + 1e-16f);
  bf16x4 ob = { (bf16_t)(acc.x*inv), (bf16_t)(acc.y*inv), (bf16_t)(acc.z*inv), (bf16_t)(acc.w*inv) };
  *(bf16x4*)(aggb + (size_t)i*256 + h*128 + d) = ob;
}

// ---------- launch ----------
extern "C" void kernel_launch(void* const* d_in, const int* in_sizes, int n_in,
                              void* d_out, int out_size, void* d_ws, size_t ws_size,
                              hipStream_t stream)
{
  const float* x     = (const float*)d_in[0];
  const int*   ei    = (const int*)d_in[1];
  const float* Wkqv  = (const float*)d_in[2];
  const float* bkqv  = (const float*)d_in[3];
  const float* W1    = (const float*)d_in[4];
  const float* b1    = (const float*)d_in[5];
  const float* W2    = (const float*)d_in[6];
  const float* b2    = (const float*)d_in[7];
  const float* Wout  = (const float*)d_in[8];
  const float* bout  = (const float*)d_in[9];
  float* out = (float*)d_out;

  const int N  = in_sizes[0] / EMB;   // 50000
  const int E0 = in_sizes[1] / 2;     // 100000
  const int E  = 2*E0 + N;            // 250000

  // workspace layout (fp32-word offsets; all 16B-aligned)
  float* base = (float*)d_ws;
  bf16_t* WcombT = (bf16_t*)base;                       // 768*256 bf16
  float*  bcomb  = base + 98304;                        // 768 w
  bf16_t* WoutT  = (bf16_t*)(base + 98304 + 768);       // 256*256 bf16
  bf16_t* xb     = (bf16_t*)(base + 131840);            // N*256 bf16
  bf16_t* Pb     = (bf16_t*)(base + 131840 + 6400000);  // N*768 bf16
  bf16_t* aggb   = (bf16_t*)(Pb + (size_t)N*768);       // N*256 bf16
  int* deg       = (int*)(aggb + (size_t)N*256);        // N
  int* cursor    = deg + N;                             // N
  int* flag      = cursor + N;                          // 1 (unused)
  int* off       = flag + 1;                            // N+1
  int* bj        = off + (N+1);                         // E
  // scratch for scan block sums: reuse aggb region (written only later by attn)
  int* bsum      = (int*)aggb;                          // <=1024 ints

  hipMemsetAsync(deg, 0, (size_t)2*N*sizeof(int), stream);  // deg + cursor

  cvt_x_kernel<<<((N*EMB/4)+255)/256,256,0,stream>>>(x, xb, N*EMB/4);
  prep_weights<<<dim3(3,257),256,0,stream>>>(Wkqv, bkqv, W1, WcombT, bcomb);
  prep_wout<<<256,256,0,stream>>>(Wout, WoutT);

  deg_kernel<<<(2*E0+255)/256,256,0,stream>>>(ei, deg, E0, N);
  const int nb = (N + 1023)/1024;
  scan1_kernel<<<nb,1024,0,stream>>>(deg, off, bsum, N);
  scan2_kernel<<<1,1024,0,stream>>>(bsum, off, nb, N);
  scan3_kernel<<<(N+255)/256,256,0,stream>>>(off, bsum, N);
  scatter_kernel<<<(E+255)/256,256,0,stream>>>(ei, off, cursor, bj, E0, N);

  // gemm<0>: 256x256 tiles (m-strips of 256, padded to mult of 8 for XCD swizzle)
  const int nm256 = (((N+255)/256) + 7) & ~7;   // 200
  mfma_gemm256<<<nm256*3,1024,0,stream>>>(xb, WcombT, bcomb, Pb, N, 768);
  fused_attn_kernel<<<(N+3)/4,256,0,stream>>>(Pb, bj, off, b1, W2, b2, aggb, N);
  // gemm<1>: 128x128 tiles
  const int nm128 = (((N+127)/128) + 7) & ~7;   // 392
  mfma_gemm_m1<<<nm128*2,512,0,stream>>>(aggb, WoutT, bout, out, N, 256, deg, x);
}